// Round 7
// baseline (285.424 us; speedup 1.0000x reference)
//
#include <hip/hip_runtime.h>

#define N_NODES 50000
#define N_EDGES 1600000
#define E_TOT   (N_EDGES + N_NODES)   // 1,650,000 incl. self-loops
#define IN_CH   128
#define C1      64                    // heads(2) * hid(32)
#define OUT_CH  128
#define N_GRAPHS 64
#define NEG_SLOPE 0.2f

#define BSH   7                        // 128 dsts per bucket
#define NBUCK ((N_NODES + 127) / 128)  // 391
#define BCAP  5120                     // per-bucket region cap (mean 4220, ~14 sigma)
#define CHUNK 8192                     // edges per k_bin workgroup
#define PN    32                       // nodes per k_pool block
#define ATTN_BLOCKS 2048               // persistent waves: 8 blocks/CU

typedef __attribute__((ext_vector_type(8))) short bf16x8;
typedef __attribute__((ext_vector_type(4))) float f32x4;
typedef __attribute__((ext_vector_type(2))) float f32x2;

__device__ __forceinline__ float elu_f(float v) {
    return v > 0.f ? v : (__expf(v) - 1.f);
}
__device__ __forceinline__ unsigned short f2bf(float f) {   // RNE
    unsigned u = __float_as_uint(f);
    return (unsigned short)((u + 0x7FFFu + ((u >> 16) & 1u)) >> 16);
}
__device__ __forceinline__ float bf_lo(unsigned u) { return __uint_as_float(u << 16); }
__device__ __forceinline__ float bf_hi(unsigned u) { return __uint_as_float(u & 0xFFFF0000u); }
__device__ __forceinline__ unsigned char f2fp8(float v) {   // OCP e4m3 via HW cvt
    return (unsigned char)(__builtin_amdgcn_cvt_pk_fp8_f32(v, v, 0, false) & 0xFF);
}
__device__ __forceinline__ float lrelu_exp(float e) {
    e = e > 0.f ? e : NEG_SLOPE * e;
    return __expf(e);
}

// ---------------- GEMM1 via MFMA: xl1(bf16) = x @ W1, fused attention dots ---
__global__ __launch_bounds__(256) void k_gemm1(
    const float* __restrict__ x, const float* __restrict__ W1,
    const float* __restrict__ att_s, const float* __restrict__ att_d,
    unsigned short* __restrict__ xl1, float* __restrict__ a_s, float* __restrict__ a_d)
{
    __shared__ unsigned short W1T[64][136];  // W1^T bf16, +8 pad (17.4 KB)
    __shared__ float psA[4][16], psD[4][16];
    const int t = threadIdx.x, wave = t >> 6, lane = t & 63;
    const int quad = lane >> 4, lm = lane & 15;
    for (int i = t; i < 128 * 64; i += 256)
        W1T[i & 63][i >> 6] = f2bf(W1[i]);   // W1T[c][k] = W1[k][c]
    __syncthreads();

    const int n0 = wave * 16;
    const int c  = n0 + lm;                  // this lane's output column
    bf16x8 bfr[4];
    #pragma unroll
    for (int s = 0; s < 4; ++s)
        bfr[s] = *(const bf16x8*)&W1T[c][s * 32 + quad * 8];
    const float asc = att_s[c], adc = att_d[c];

    const int r0 = blockIdx.x * 16;
    f32x4 acc = {0.f, 0.f, 0.f, 0.f};
    #pragma unroll
    for (int s = 0; s < 4; ++s) {
        const float* xp = &x[(size_t)(r0 + lm) * 128 + s * 32 + quad * 8];
        float4 xa = *(const float4*)xp;
        float4 xb = *(const float4*)(xp + 4);
        bf16x8 afr;
        afr[0] = (short)f2bf(xa.x); afr[1] = (short)f2bf(xa.y);
        afr[2] = (short)f2bf(xa.z); afr[3] = (short)f2bf(xa.w);
        afr[4] = (short)f2bf(xb.x); afr[5] = (short)f2bf(xb.y);
        afr[6] = (short)f2bf(xb.z); afr[7] = (short)f2bf(xb.w);
        acc = __builtin_amdgcn_mfma_f32_16x16x32_bf16(afr, bfr[s], acc, 0, 0, 0);
    }
    float psv[4], pdv[4];
    #pragma unroll
    for (int r = 0; r < 4; ++r) {
        float v = acc[r];
        xl1[(size_t)(r0 + quad * 4 + r) * 64 + c] = f2bf(v);
        psv[r] = v * asc;
        pdv[r] = v * adc;
    }
    #pragma unroll
    for (int ofs = 1; ofs <= 8; ofs <<= 1) {
        #pragma unroll
        for (int r = 0; r < 4; ++r) {
            psv[r] += __shfl_xor(psv[r], ofs, 64);
            pdv[r] += __shfl_xor(pdv[r], ofs, 64);
        }
    }
    if (lm == 0) {
        #pragma unroll
        for (int r = 0; r < 4; ++r) {
            psA[wave][quad * 4 + r] = psv[r];
            psD[wave][quad * 4 + r] = pdv[r];
        }
    }
    __syncthreads();
    if (t < 32) {
        const int row = t & 15, h = t >> 4;
        a_s[(size_t)(r0 + row) * 2 + h] = psA[2 * h][row] + psA[2 * h + 1][row];
        a_d[(size_t)(r0 + row) * 2 + h] = psD[2 * h][row] + psD[2 * h + 1][row];
    }
}

// ---------------- pass 1: LDS-staged binning by dst>>7 ----------------------
__global__ __launch_bounds__(256) void k_bin(
    const int* __restrict__ ei, int* __restrict__ gcur, unsigned* __restrict__ bbuf)
{
    __shared__ int cnt[512];
    __shared__ int base[NBUCK];
    __shared__ int cnt2[NBUCK];
    __shared__ int gpos[NBUCK];
    __shared__ unsigned stage[CHUNK];      // 32 KB
    __shared__ unsigned short bof[CHUNK];  // 16 KB
    const int t = threadIdx.x;
    const long long e0 = (long long)blockIdx.x * CHUNK;
    const int nE = (int)min((long long)CHUNK, (long long)E_TOT - e0);

    cnt[t] = 0; cnt[t + 256] = 0;
    for (int b = t; b < NBUCK; b += 256) cnt2[b] = 0;
    __syncthreads();

    const int per = CHUNK / 256;           // 32
    int myb[per]; unsigned mye[per];
    #pragma unroll
    for (int i = 0; i < per; ++i) {
        int idx = t + 256 * i;
        myb[i] = -1;
        if (idx < nE) {
            long long e = e0 + idx;
            int s, d;
            if (e < N_EDGES) { s = ei[e]; d = ei[N_EDGES + e]; }
            else             { s = d = (int)(e - N_EDGES); }
            myb[i] = d >> BSH;
            mye[i] = ((unsigned)(d & 127) << 17) | (unsigned)s;
            atomicAdd(&cnt[myb[i]], 1);
        }
    }
    __syncthreads();
    for (int ofs = 1; ofs < 512; ofs <<= 1) {
        int v0 = (t >= ofs) ? cnt[t - ofs] : 0;
        int v1 = cnt[t + 256 - ofs];
        __syncthreads();
        cnt[t] += v0; cnt[t + 256] += v1;
        __syncthreads();
    }
    for (int b = t; b < NBUCK; b += 256) {
        base[b] = (b == 0) ? 0 : cnt[b - 1];
        int c = cnt[b] - base[b];
        gpos[b] = (c > 0) ? atomicAdd(&gcur[b], c) : 0;
    }
    __syncthreads();
    #pragma unroll
    for (int i = 0; i < per; ++i) {
        if (myb[i] >= 0) {
            int slot = base[myb[i]] + atomicAdd(&cnt2[myb[i]], 1);
            stage[slot] = mye[i];
            bof[slot] = (unsigned short)myb[i];
        }
    }
    __syncthreads();
    for (int i = t; i < nE; i += 256) {
        int b = bof[i];
        int pos = gpos[b] + (i - base[b]);
        if (pos < BCAP)
            bbuf[(size_t)b * BCAP + pos] = stage[i];
    }
}

// -------- pass 2: per-bucket counting sort, emits beg/end (light version) ---
__global__ __launch_bounds__(256) void k_bsort(
    const int* __restrict__ gcur, unsigned* __restrict__ bbuf,
    int* __restrict__ beg, int* __restrict__ end)
{
    __shared__ unsigned est[BCAP];   // 20 KB
    __shared__ unsigned sst[BCAP];   // 20 KB
    __shared__ int c[128], lbase[128], c2[128];
    const int b = blockIdx.x, t = threadIdx.x;
    const int n = min(gcur[b], BCAP);
    unsigned* reg = bbuf + (size_t)b * BCAP;
    for (int i = t; i < n; i += 256) est[i] = reg[i];
    if (t < 128) { c[t] = 0; c2[t] = 0; }
    __syncthreads();
    for (int i = t; i < n; i += 256) atomicAdd(&c[est[i] >> 17], 1);
    __syncthreads();
    for (int ofs = 1; ofs < 128; ofs <<= 1) {
        int v = (t < 128 && t >= ofs) ? c[t - ofs] : 0;
        __syncthreads();
        if (t < 128) c[t] += v;
        __syncthreads();
    }
    if (t < 128) {
        lbase[t] = (t == 0) ? 0 : c[t - 1];
        int dst = (b << BSH) + t;
        if (dst < N_NODES) {
            beg[dst] = b * BCAP + lbase[t];
            end[dst] = b * BCAP + c[t];
        }
    }
    __syncthreads();
    for (int i = t; i < n; i += 256) {
        unsigned v = est[i];
        int dl = (int)(v >> 17);
        int pos = lbase[dl] + atomicAdd(&c2[dl], 1);
        sst[pos] = v & 0x1FFFFu;             // strip dl bits -> pure src index
    }
    __syncthreads();
    for (int i = t; i < n; i += 256) reg[i] = sst[i];
}

// ------- layer-1 attention: persistent grid-stride waves, inline weights ----
#define FMA8(vv, ww) do { \
    acc[0] = fmaf(bf_lo(vv.x), ww, acc[0]); acc[1] = fmaf(bf_hi(vv.x), ww, acc[1]); \
    acc[2] = fmaf(bf_lo(vv.y), ww, acc[2]); acc[3] = fmaf(bf_hi(vv.y), ww, acc[3]); \
    acc[4] = fmaf(bf_lo(vv.z), ww, acc[4]); acc[5] = fmaf(bf_hi(vv.z), ww, acc[5]); \
    acc[6] = fmaf(bf_lo(vv.w), ww, acc[6]); acc[7] = fmaf(bf_hi(vv.w), ww, acc[7]); \
} while (0)

__global__ __launch_bounds__(256) void k_attn1(
    const int* __restrict__ beg_a, const int* __restrict__ end_a,
    const unsigned* __restrict__ csr,
    const float* __restrict__ a_s, const float* __restrict__ a_d,
    const unsigned short* __restrict__ xl, const float* __restrict__ b1,
    unsigned short* __restrict__ hout)    // [N][64] bf16: elu(aggregate + b1)
{
    const int wave = threadIdx.x >> 6, lane = threadIdx.x & 63;
    const int li = lane & 7, sub = lane >> 3, hh = li >> 2;
    const int nw = gridDim.x * 4;
    const float4 b1a = *(const float4*)&b1[li * 8];
    const float4 b1b = *(const float4*)&b1[li * 8 + 4];

    for (int dst = blockIdx.x * 4 + wave; dst < N_NODES; dst += nw) {
        const int beg = beg_a[dst], end = end_a[dst];
        const float adh = a_d[(size_t)dst * 2 + hh];   // wave-uniform per head

        float acc[8];
        #pragma unroll
        for (int i = 0; i < 8; ++i) acc[i] = 0.f;
        float wsum = 0.f;

        int k = beg;
        // main loop: all 32 slots valid, no masks, no clamps
        for (; k + 32 <= end; k += 32) {
            const int i0 = k + sub;
            const int s0 = (int)csr[i0];
            const int s1 = (int)csr[i0 + 8];
            const int s2 = (int)csr[i0 + 16];
            const int s3 = (int)csr[i0 + 24];
            const float w0 = lrelu_exp(a_s[(size_t)s0 * 2 + hh] + adh);
            const float w1 = lrelu_exp(a_s[(size_t)s1 * 2 + hh] + adh);
            const float w2 = lrelu_exp(a_s[(size_t)s2 * 2 + hh] + adh);
            const float w3 = lrelu_exp(a_s[(size_t)s3 * 2 + hh] + adh);
            uint4 v0 = *(const uint4*)&xl[(size_t)s0 * 64 + li * 8];
            uint4 v1 = *(const uint4*)&xl[(size_t)s1 * 64 + li * 8];
            uint4 v2 = *(const uint4*)&xl[(size_t)s2 * 64 + li * 8];
            uint4 v3 = *(const uint4*)&xl[(size_t)s3 * 64 + li * 8];
            wsum += w0 + w1 + w2 + w3;
            FMA8(v0, w0);
            FMA8(v1, w1);
            FMA8(v2, w2);
            FMA8(v3, w3);
        }
        // tail: 8 edges per iteration, masked
        const int last = end - 1;          // >= beg (self-loop guarantees >=1 edge)
        for (; k < end; k += 8) {
            const int i0 = k + sub;
            const int c0 = min(i0, last);
            const int s0 = (int)csr[c0];
            float w0 = lrelu_exp(a_s[(size_t)s0 * 2 + hh] + adh);
            if (i0 >= end) w0 = 0.f;
            uint4 v0 = *(const uint4*)&xl[(size_t)s0 * 64 + li * 8];
            wsum += w0;
            FMA8(v0, w0);
        }
        #pragma unroll
        for (int ofs = 8; ofs <= 32; ofs <<= 1) {
            wsum += __shfl_xor(wsum, ofs, 64);
            #pragma unroll
            for (int i = 0; i < 8; ++i) acc[i] += __shfl_xor(acc[i], ofs, 64);
        }
        if (sub == 0) {
            const float inv = 1.f / wsum;
            float h0 = elu_f(acc[0] * inv + b1a.x);
            float h1 = elu_f(acc[1] * inv + b1a.y);
            float h2 = elu_f(acc[2] * inv + b1a.z);
            float h3 = elu_f(acc[3] * inv + b1a.w);
            float h4 = elu_f(acc[4] * inv + b1b.x);
            float h5 = elu_f(acc[5] * inv + b1b.y);
            float h6 = elu_f(acc[6] * inv + b1b.z);
            float h7 = elu_f(acc[7] * inv + b1b.w);
            uint4 p;
            p.x = (unsigned)f2bf(h0) | ((unsigned)f2bf(h1) << 16);
            p.y = (unsigned)f2bf(h2) | ((unsigned)f2bf(h3) << 16);
            p.z = (unsigned)f2bf(h4) | ((unsigned)f2bf(h5) << 16);
            p.w = (unsigned)f2bf(h6) | ((unsigned)f2bf(h7) << 16);
            *(uint4*)&hout[(size_t)dst * 64 + li * 8] = p;
        }
    }
}

// ---------------- GEMM2 via MFMA: xl2(fp8) = h @ W2, fused attention dots ----
__global__ __launch_bounds__(256) void k_gemm2m(
    const unsigned short* __restrict__ h, const float* __restrict__ W2,
    const float* __restrict__ att_s, const float* __restrict__ att_d,
    unsigned char* __restrict__ xl2, float* __restrict__ a_s, float* __restrict__ a_d)
{
    __shared__ unsigned short W2T[128][72];  // W2^T bf16, pad 72 (18.4 KB)
    __shared__ float psA[4][16], psD[4][16];
    const int t = threadIdx.x, wave = t >> 6, lane = t & 63;
    const int quad = lane >> 4, lm = lane & 15;
    for (int i = t; i < 64 * 128; i += 256)
        W2T[i & 127][i >> 7] = f2bf(W2[i]);  // W2T[c][k] = W2[k][c]
    __syncthreads();

    const int c0 = wave * 32 + lm;
    const int c1 = c0 + 16;
    bf16x8 bfr0[2], bfr1[2];
    #pragma unroll
    for (int s = 0; s < 2; ++s) {
        bfr0[s] = *(const bf16x8*)&W2T[c0][s * 32 + quad * 8];
        bfr1[s] = *(const bf16x8*)&W2T[c1][s * 32 + quad * 8];
    }
    const float as0 = att_s[c0], as1 = att_s[c1];
    const float ad0 = att_d[c0], ad1 = att_d[c1];

    const int r0 = blockIdx.x * 16;
    f32x4 acc0 = {0.f, 0.f, 0.f, 0.f}, acc1 = {0.f, 0.f, 0.f, 0.f};
    #pragma unroll
    for (int s = 0; s < 2; ++s) {
        bf16x8 afr = *(const bf16x8*)&h[(size_t)(r0 + lm) * 64 + s * 32 + quad * 8];
        acc0 = __builtin_amdgcn_mfma_f32_16x16x32_bf16(afr, bfr0[s], acc0, 0, 0, 0);
        acc1 = __builtin_amdgcn_mfma_f32_16x16x32_bf16(afr, bfr1[s], acc1, 0, 0, 0);
    }
    float psv[4], pdv[4];
    #pragma unroll
    for (int r = 0; r < 4; ++r) {
        float v0 = acc0[r], v1 = acc1[r];
        const size_t row = (size_t)(r0 + quad * 4 + r) * 128;
        xl2[row + c0] = f2fp8(v0);          // fp8 e4m3 gather table
        xl2[row + c1] = f2fp8(v1);
        psv[r] = v0 * as0 + v1 * as1;       // logits from fp32 (pre-quant)
        pdv[r] = v0 * ad0 + v1 * ad1;
    }
    #pragma unroll
    for (int ofs = 1; ofs <= 8; ofs <<= 1) {
        #pragma unroll
        for (int r = 0; r < 4; ++r) {
            psv[r] += __shfl_xor(psv[r], ofs, 64);
            pdv[r] += __shfl_xor(pdv[r], ofs, 64);
        }
    }
    if (lm == 0) {
        #pragma unroll
        for (int r = 0; r < 4; ++r) {
            psA[wave][quad * 4 + r] = psv[r];
            psD[wave][quad * 4 + r] = pdv[r];
        }
    }
    __syncthreads();
    if (t < 16) {
        a_s[r0 + t] = psA[0][t] + psA[1][t] + psA[2][t] + psA[3][t];
        a_d[r0 + t] = psD[0][t] + psD[1][t] + psD[2][t] + psD[3][t];
    }
}

// ------- layer-2 attention: persistent waves, fp8 gather, bf16 out ----------
#define CFMA16(vv, ww) do { \
    f32x2 p_; \
    p_ = __builtin_amdgcn_cvt_pk_f32_fp8(vv.x, false); acc[0]  = fmaf(p_.x, ww, acc[0]);  acc[1]  = fmaf(p_.y, ww, acc[1]);  \
    p_ = __builtin_amdgcn_cvt_pk_f32_fp8(vv.x, true);  acc[2]  = fmaf(p_.x, ww, acc[2]);  acc[3]  = fmaf(p_.y, ww, acc[3]);  \
    p_ = __builtin_amdgcn_cvt_pk_f32_fp8(vv.y, false); acc[4]  = fmaf(p_.x, ww, acc[4]);  acc[5]  = fmaf(p_.y, ww, acc[5]);  \
    p_ = __builtin_amdgcn_cvt_pk_f32_fp8(vv.y, true);  acc[6]  = fmaf(p_.x, ww, acc[6]);  acc[7]  = fmaf(p_.y, ww, acc[7]);  \
    p_ = __builtin_amdgcn_cvt_pk_f32_fp8(vv.z, false); acc[8]  = fmaf(p_.x, ww, acc[8]);  acc[9]  = fmaf(p_.y, ww, acc[9]);  \
    p_ = __builtin_amdgcn_cvt_pk_f32_fp8(vv.z, true);  acc[10] = fmaf(p_.x, ww, acc[10]); acc[11] = fmaf(p_.y, ww, acc[11]); \
    p_ = __builtin_amdgcn_cvt_pk_f32_fp8(vv.w, false); acc[12] = fmaf(p_.x, ww, acc[12]); acc[13] = fmaf(p_.y, ww, acc[13]); \
    p_ = __builtin_amdgcn_cvt_pk_f32_fp8(vv.w, true);  acc[14] = fmaf(p_.x, ww, acc[14]); acc[15] = fmaf(p_.y, ww, acc[15]); \
} while (0)

__global__ __launch_bounds__(256) void k_attn2(
    const int* __restrict__ beg_a, const int* __restrict__ end_a,
    const unsigned* __restrict__ csr,
    const float* __restrict__ a_s, const float* __restrict__ a_d,
    const unsigned char* __restrict__ xl, unsigned short* __restrict__ out)
{
    const int wave = threadIdx.x >> 6, lane = threadIdx.x & 63;
    const int li = lane & 7, sub = lane >> 3;   // ch group li*16..+15; edge slot
    const int nw = gridDim.x * 4;

    for (int dst = blockIdx.x * 4 + wave; dst < N_NODES; dst += nw) {
        const int beg = beg_a[dst], end = end_a[dst];
        const float ad0 = a_d[dst];             // wave-uniform

        float acc[16];
        #pragma unroll
        for (int i = 0; i < 16; ++i) acc[i] = 0.f;
        float wsum = 0.f;

        int k = beg;
        // main loop: all 32 slots valid, no masks, no clamps
        for (; k + 32 <= end; k += 32) {
            const int i0 = k + sub;
            const int s0 = (int)csr[i0];
            const int s1 = (int)csr[i0 + 8];
            const int s2 = (int)csr[i0 + 16];
            const int s3 = (int)csr[i0 + 24];
            const float w0 = lrelu_exp(a_s[s0] + ad0);
            const float w1 = lrelu_exp(a_s[s1] + ad0);
            const float w2 = lrelu_exp(a_s[s2] + ad0);
            const float w3 = lrelu_exp(a_s[s3] + ad0);
            uint4 v0 = *(const uint4*)&xl[(size_t)s0 * 128 + li * 16];
            uint4 v1 = *(const uint4*)&xl[(size_t)s1 * 128 + li * 16];
            uint4 v2 = *(const uint4*)&xl[(size_t)s2 * 128 + li * 16];
            uint4 v3 = *(const uint4*)&xl[(size_t)s3 * 128 + li * 16];
            wsum += w0 + w1 + w2 + w3;
            CFMA16(v0, w0);
            CFMA16(v1, w1);
            CFMA16(v2, w2);
            CFMA16(v3, w3);
        }
        // tail: 8 edges per iteration, masked
        const int last = end - 1;
        for (; k < end; k += 8) {
            const int i0 = k + sub;
            const int c0 = min(i0, last);
            const int s0 = (int)csr[c0];
            float w0 = lrelu_exp(a_s[s0] + ad0);
            if (i0 >= end) w0 = 0.f;
            uint4 v0 = *(const uint4*)&xl[(size_t)s0 * 128 + li * 16];
            wsum += w0;
            CFMA16(v0, w0);
        }
        #pragma unroll
        for (int ofs = 8; ofs <= 32; ofs <<= 1) {
            wsum += __shfl_xor(wsum, ofs, 64);
            #pragma unroll
            for (int i = 0; i < 16; ++i) acc[i] += __shfl_xor(acc[i], ofs, 64);
        }
        if (sub == 0) {
            const float inv = 1.f / wsum;
            unsigned short* op = &out[(size_t)dst * 128 + li * 16];
            uint4 pa, pb;
            pa.x = (unsigned)f2bf(acc[0]  * inv) | ((unsigned)f2bf(acc[1]  * inv) << 16);
            pa.y = (unsigned)f2bf(acc[2]  * inv) | ((unsigned)f2bf(acc[3]  * inv) << 16);
            pa.z = (unsigned)f2bf(acc[4]  * inv) | ((unsigned)f2bf(acc[5]  * inv) << 16);
            pa.w = (unsigned)f2bf(acc[6]  * inv) | ((unsigned)f2bf(acc[7]  * inv) << 16);
            pb.x = (unsigned)f2bf(acc[8]  * inv) | ((unsigned)f2bf(acc[9]  * inv) << 16);
            pb.y = (unsigned)f2bf(acc[10] * inv) | ((unsigned)f2bf(acc[11] * inv) << 16);
            pb.z = (unsigned)f2bf(acc[12] * inv) | ((unsigned)f2bf(acc[13] * inv) << 16);
            pb.w = (unsigned)f2bf(acc[14] * inv) | ((unsigned)f2bf(acc[15] * inv) << 16);
            *(uint4*)op       = pa;
            *(uint4*)(op + 8) = pb;
        }
    }
}

// ---------------- pooling: 32 nodes/block, 2 node-lanes x 128 ch (bf16 in) ---
__global__ __launch_bounds__(256) void k_pool(
    const unsigned short* __restrict__ out2, const float* __restrict__ b2,
    const int* __restrict__ batch, float* __restrict__ sums, float* __restrict__ cnts)
{
    const int c    = threadIdx.x & 127;
    const int half = threadIdx.x >> 7;
    const int n0   = blockIdx.x * PN;
    const int nb   = n0 + half;
    if (nb >= N_NODES) return;
    const float bc = b2[c];
    float acc = 0.f;
    int cur = batch[nb], cnt = 0;
    for (int i = half; i < PN; i += 2) {
        int n = n0 + i;
        if (n >= N_NODES) break;
        int g = batch[n];
        if (g != cur) {
            atomicAdd(&sums[cur * OUT_CH + c], acc);
            if (c == 0) atomicAdd(&cnts[cur], (float)cnt);
            acc = 0.f; cnt = 0; cur = g;
        }
        float v = __uint_as_float((unsigned)out2[(size_t)n * OUT_CH + c] << 16);
        acc += elu_f(v + bc);
        cnt++;
    }
    if (cnt > 0) {
        atomicAdd(&sums[cur * OUT_CH + c], acc);
        if (c == 0) atomicAdd(&cnts[cur], (float)cnt);
    }
}

__global__ __launch_bounds__(256) void k_final(
    const float* __restrict__ sums, const float* __restrict__ cnts,
    float* __restrict__ out)
{
    int i = blockIdx.x * 256 + threadIdx.x;
    if (i >= N_GRAPHS * OUT_CH) return;
    out[i] = sums[i] / fmaxf(cnts[i >> 7], 1.f);
}

extern "C" void kernel_launch(void* const* d_in, const int* in_sizes, int n_in,
                              void* d_out, int out_size, void* d_ws, size_t ws_size,
                              hipStream_t stream)
{
    const float* x    = (const float*)d_in[0];
    const int*   ei   = (const int*)d_in[1];
    const int*   batch= (const int*)d_in[2];
    const float* W1   = (const float*)d_in[3];
    const float* as1  = (const float*)d_in[4];
    const float* ad1  = (const float*)d_in[5];
    const float* b1   = (const float*)d_in[6];
    const float* W2   = (const float*)d_in[7];
    const float* as2  = (const float*)d_in[8];
    const float* ad2  = (const float*)d_in[9];
    const float* b2   = (const float*)d_in[10];

    float* ws = (float*)d_ws;
    size_t o = 0;
    unsigned short* xl1b = (unsigned short*)(ws + o); o += (size_t)N_NODES * C1 / 2;
    unsigned short* hbuf = (unsigned short*)(ws + o); o += (size_t)N_NODES * C1 / 2;
    unsigned char*  xl2q = (unsigned char*)(ws + o);  o += (size_t)N_NODES * OUT_CH / 4;
    float*    a_s1 = ws + o; o += (size_t)N_NODES * 2;
    float*    a_d1 = ws + o; o += (size_t)N_NODES * 2;
    float*    a_s2 = ws + o; o += (size_t)N_NODES;
    float*    a_d2 = ws + o; o += (size_t)N_NODES;
    unsigned short* out2b = (unsigned short*)(ws + o); o += (size_t)N_NODES * OUT_CH / 2;
    unsigned* bbuf = (unsigned*)(ws + o); o += (size_t)NBUCK * BCAP;
    int*      beg  = (int*)(ws + o); o += (size_t)N_NODES;
    int*      end  = (int*)(ws + o); o += (size_t)N_NODES;
    size_t zero_start = o;
    int*      gcur = (int*)(ws + o); o += (size_t)NBUCK;
    float*    sums = ws + o;         o += (size_t)N_GRAPHS * OUT_CH;
    float*    cnts = ws + o;         o += (size_t)N_GRAPHS;
    size_t zero_bytes = (o - zero_start) * sizeof(float);
    hipMemsetAsync(ws + zero_start, 0, zero_bytes, stream);

    const int nchunks = (E_TOT + CHUNK - 1) / CHUNK;   // 202

    k_gemm1<<<N_NODES / 16, 256, 0, stream>>>(x, W1, as1, ad1, xl1b, a_s1, a_d1);
    k_bin<<<nchunks, 256, 0, stream>>>(ei, gcur, bbuf);
    k_bsort<<<NBUCK, 256, 0, stream>>>(gcur, bbuf, beg, end);
    k_attn1<<<ATTN_BLOCKS, 256, 0, stream>>>(beg, end, bbuf, a_s1, a_d1, xl1b, b1, hbuf);
    k_gemm2m<<<(N_NODES + 15) / 16, 256, 0, stream>>>(hbuf, W2, as2, ad2, xl2q, a_s2, a_d2);
    k_attn2<<<ATTN_BLOCKS, 256, 0, stream>>>(beg, end, bbuf, a_s2, a_d2, xl2q, out2b);
    k_pool<<<(N_NODES + PN - 1) / PN, 256, 0, stream>>>(out2b, b2, batch, sums, cnts);
    k_final<<<(N_GRAPHS * OUT_CH + 255) / 256, 256, 0, stream>>>(sums, cnts, (float*)d_out);
}

// Round 8
// 261.143 us; speedup vs baseline: 1.0930x; 1.0930x over previous
//
#include <hip/hip_runtime.h>

#define N_NODES 50000
#define N_EDGES 1600000
#define E_TOT   (N_EDGES + N_NODES)   // 1,650,000 incl. self-loops
#define IN_CH   128
#define C1      64                    // heads(2) * hid(32)
#define OUT_CH  128
#define N_GRAPHS 64
#define NEG_SLOPE 0.2f

#define BSH   7                        // 128 dsts per bucket
#define NBUCK ((N_NODES + 127) / 128)  // 391
#define BCAP  5120                     // per-bucket region cap (mean 4220, ~14 sigma)
#define CHUNK 8192                     // edges per k_bin workgroup
#define PN    32                       // nodes per k_pool block

typedef __attribute__((ext_vector_type(8))) short bf16x8;
typedef __attribute__((ext_vector_type(4))) float f32x4;
typedef __attribute__((ext_vector_type(2))) float f32x2;

__device__ __forceinline__ float elu_f(float v) {
    return v > 0.f ? v : (__expf(v) - 1.f);
}
__device__ __forceinline__ unsigned short f2bf(float f) {   // RNE
    unsigned u = __float_as_uint(f);
    return (unsigned short)((u + 0x7FFFu + ((u >> 16) & 1u)) >> 16);
}
__device__ __forceinline__ float bf_lo(unsigned u) { return __uint_as_float(u << 16); }
__device__ __forceinline__ float bf_hi(unsigned u) { return __uint_as_float(u & 0xFFFF0000u); }
__device__ __forceinline__ unsigned char f2fp8(float v) {   // OCP e4m3 via HW cvt
    return (unsigned char)(__builtin_amdgcn_cvt_pk_fp8_f32(v, v, 0, false) & 0xFF);
}
__device__ __forceinline__ float lrelu_exp(float e) {
    e = e > 0.f ? e : NEG_SLOPE * e;
    return __expf(e);
}

// ---------------- GEMM1 via MFMA: xl1(bf16) = x @ W1, fused attention dots ---
__global__ __launch_bounds__(256) void k_gemm1(
    const float* __restrict__ x, const float* __restrict__ W1,
    const float* __restrict__ att_s, const float* __restrict__ att_d,
    unsigned short* __restrict__ xl1, float* __restrict__ a_s, float* __restrict__ a_d)
{
    __shared__ unsigned short W1T[64][136];  // W1^T bf16, +8 pad (17.4 KB)
    __shared__ float psA[4][16], psD[4][16];
    const int t = threadIdx.x, wave = t >> 6, lane = t & 63;
    const int quad = lane >> 4, lm = lane & 15;
    for (int i = t; i < 128 * 64; i += 256)
        W1T[i & 63][i >> 6] = f2bf(W1[i]);   // W1T[c][k] = W1[k][c]
    __syncthreads();

    const int n0 = wave * 16;
    const int c  = n0 + lm;                  // this lane's output column
    bf16x8 bfr[4];
    #pragma unroll
    for (int s = 0; s < 4; ++s)
        bfr[s] = *(const bf16x8*)&W1T[c][s * 32 + quad * 8];
    const float asc = att_s[c], adc = att_d[c];

    const int r0 = blockIdx.x * 16;
    f32x4 acc = {0.f, 0.f, 0.f, 0.f};
    #pragma unroll
    for (int s = 0; s < 4; ++s) {
        const float* xp = &x[(size_t)(r0 + lm) * 128 + s * 32 + quad * 8];
        float4 xa = *(const float4*)xp;
        float4 xb = *(const float4*)(xp + 4);
        bf16x8 afr;
        afr[0] = (short)f2bf(xa.x); afr[1] = (short)f2bf(xa.y);
        afr[2] = (short)f2bf(xa.z); afr[3] = (short)f2bf(xa.w);
        afr[4] = (short)f2bf(xb.x); afr[5] = (short)f2bf(xb.y);
        afr[6] = (short)f2bf(xb.z); afr[7] = (short)f2bf(xb.w);
        acc = __builtin_amdgcn_mfma_f32_16x16x32_bf16(afr, bfr[s], acc, 0, 0, 0);
    }
    float psv[4], pdv[4];
    #pragma unroll
    for (int r = 0; r < 4; ++r) {
        float v = acc[r];
        xl1[(size_t)(r0 + quad * 4 + r) * 64 + c] = f2bf(v);
        psv[r] = v * asc;
        pdv[r] = v * adc;
    }
    #pragma unroll
    for (int ofs = 1; ofs <= 8; ofs <<= 1) {
        #pragma unroll
        for (int r = 0; r < 4; ++r) {
            psv[r] += __shfl_xor(psv[r], ofs, 64);
            pdv[r] += __shfl_xor(pdv[r], ofs, 64);
        }
    }
    if (lm == 0) {
        #pragma unroll
        for (int r = 0; r < 4; ++r) {
            psA[wave][quad * 4 + r] = psv[r];
            psD[wave][quad * 4 + r] = pdv[r];
        }
    }
    __syncthreads();
    if (t < 32) {
        const int row = t & 15, h = t >> 4;
        a_s[(size_t)(r0 + row) * 2 + h] = psA[2 * h][row] + psA[2 * h + 1][row];
        a_d[(size_t)(r0 + row) * 2 + h] = psD[2 * h][row] + psD[2 * h + 1][row];
    }
}

// ---------------- pass 1: LDS-staged binning by dst>>7 ----------------------
__global__ __launch_bounds__(256) void k_bin(
    const int* __restrict__ ei, int* __restrict__ gcur, unsigned* __restrict__ bbuf)
{
    __shared__ int cnt[512];
    __shared__ int base[NBUCK];
    __shared__ int cnt2[NBUCK];
    __shared__ int gpos[NBUCK];
    __shared__ unsigned stage[CHUNK];      // 32 KB
    __shared__ unsigned short bof[CHUNK];  // 16 KB
    const int t = threadIdx.x;
    const long long e0 = (long long)blockIdx.x * CHUNK;
    const int nE = (int)min((long long)CHUNK, (long long)E_TOT - e0);

    cnt[t] = 0; cnt[t + 256] = 0;
    for (int b = t; b < NBUCK; b += 256) cnt2[b] = 0;
    __syncthreads();

    const int per = CHUNK / 256;           // 32
    int myb[per]; unsigned mye[per];
    #pragma unroll
    for (int i = 0; i < per; ++i) {
        int idx = t + 256 * i;
        myb[i] = -1;
        if (idx < nE) {
            long long e = e0 + idx;
            int s, d;
            if (e < N_EDGES) { s = ei[e]; d = ei[N_EDGES + e]; }
            else             { s = d = (int)(e - N_EDGES); }
            myb[i] = d >> BSH;
            mye[i] = ((unsigned)(d & 127) << 17) | (unsigned)s;
            atomicAdd(&cnt[myb[i]], 1);
        }
    }
    __syncthreads();
    for (int ofs = 1; ofs < 512; ofs <<= 1) {
        int v0 = (t >= ofs) ? cnt[t - ofs] : 0;
        int v1 = cnt[t + 256 - ofs];
        __syncthreads();
        cnt[t] += v0; cnt[t + 256] += v1;
        __syncthreads();
    }
    for (int b = t; b < NBUCK; b += 256) {
        base[b] = (b == 0) ? 0 : cnt[b - 1];
        int c = cnt[b] - base[b];
        gpos[b] = (c > 0) ? atomicAdd(&gcur[b], c) : 0;
    }
    __syncthreads();
    #pragma unroll
    for (int i = 0; i < per; ++i) {
        if (myb[i] >= 0) {
            int slot = base[myb[i]] + atomicAdd(&cnt2[myb[i]], 1);
            stage[slot] = mye[i];
            bof[slot] = (unsigned short)myb[i];
        }
    }
    __syncthreads();
    for (int i = t; i < nE; i += 256) {
        int b = bof[i];
        int pos = gpos[b] + (i - base[b]);
        if (pos < BCAP)
            bbuf[(size_t)b * BCAP + pos] = stage[i];
    }
}

// -------- pass 2: per-bucket counting sort, emits beg/end (light version) ---
__global__ __launch_bounds__(256) void k_bsort(
    const int* __restrict__ gcur, unsigned* __restrict__ bbuf,
    int* __restrict__ beg, int* __restrict__ end)
{
    __shared__ unsigned est[BCAP];   // 20 KB
    __shared__ unsigned sst[BCAP];   // 20 KB
    __shared__ int c[128], lbase[128], c2[128];
    const int b = blockIdx.x, t = threadIdx.x;
    const int n = min(gcur[b], BCAP);
    unsigned* reg = bbuf + (size_t)b * BCAP;
    for (int i = t; i < n; i += 256) est[i] = reg[i];
    if (t < 128) { c[t] = 0; c2[t] = 0; }
    __syncthreads();
    for (int i = t; i < n; i += 256) atomicAdd(&c[est[i] >> 17], 1);
    __syncthreads();
    for (int ofs = 1; ofs < 128; ofs <<= 1) {
        int v = (t < 128 && t >= ofs) ? c[t - ofs] : 0;
        __syncthreads();
        if (t < 128) c[t] += v;
        __syncthreads();
    }
    if (t < 128) {
        lbase[t] = (t == 0) ? 0 : c[t - 1];
        int dst = (b << BSH) + t;
        if (dst < N_NODES) {
            beg[dst] = b * BCAP + lbase[t];
            end[dst] = b * BCAP + c[t];
        }
    }
    __syncthreads();
    for (int i = t; i < n; i += 256) {
        unsigned v = est[i];
        int dl = (int)(v >> 17);
        int pos = lbase[dl] + atomicAdd(&c2[dl], 1);
        sst[pos] = v & 0x1FFFFu;             // strip dl bits -> pure src index
    }
    __syncthreads();
    for (int i = t; i < n; i += 256) reg[i] = sst[i];
}

// ------- layer-1 attention: inline per-lane weights, unguarded main loop ----
#define FMA8(vv, ww) do { \
    acc[0] = fmaf(bf_lo(vv.x), ww, acc[0]); acc[1] = fmaf(bf_hi(vv.x), ww, acc[1]); \
    acc[2] = fmaf(bf_lo(vv.y), ww, acc[2]); acc[3] = fmaf(bf_hi(vv.y), ww, acc[3]); \
    acc[4] = fmaf(bf_lo(vv.z), ww, acc[4]); acc[5] = fmaf(bf_hi(vv.z), ww, acc[5]); \
    acc[6] = fmaf(bf_lo(vv.w), ww, acc[6]); acc[7] = fmaf(bf_hi(vv.w), ww, acc[7]); \
} while (0)

__global__ __launch_bounds__(256) void k_attn1(
    const int* __restrict__ beg_a, const int* __restrict__ end_a,
    const unsigned* __restrict__ csr,
    const float* __restrict__ a_s, const float* __restrict__ a_d,
    const unsigned short* __restrict__ xl, const float* __restrict__ b1,
    unsigned short* __restrict__ hout)    // [N][64] bf16: elu(aggregate + b1)
{
    const int wave = threadIdx.x >> 6, lane = threadIdx.x & 63;
    const int dst = blockIdx.x * 4 + wave;
    const int beg = beg_a[dst], end = end_a[dst];
    const int li = lane & 7, sub = lane >> 3, hh = li >> 2;
    const float adh = a_d[(size_t)dst * 2 + hh];   // wave-uniform per head

    float acc[8];
    #pragma unroll
    for (int i = 0; i < 8; ++i) acc[i] = 0.f;
    float wsum = 0.f;

    int k = beg;
    // main loop: all 32 slots valid, no masks, no clamps
    for (; k + 32 <= end; k += 32) {
        const int i0 = k + sub;
        const int s0 = (int)csr[i0];
        const int s1 = (int)csr[i0 + 8];
        const int s2 = (int)csr[i0 + 16];
        const int s3 = (int)csr[i0 + 24];
        const float w0 = lrelu_exp(a_s[(size_t)s0 * 2 + hh] + adh);
        const float w1 = lrelu_exp(a_s[(size_t)s1 * 2 + hh] + adh);
        const float w2 = lrelu_exp(a_s[(size_t)s2 * 2 + hh] + adh);
        const float w3 = lrelu_exp(a_s[(size_t)s3 * 2 + hh] + adh);
        uint4 v0 = *(const uint4*)&xl[(size_t)s0 * 64 + li * 8];
        uint4 v1 = *(const uint4*)&xl[(size_t)s1 * 64 + li * 8];
        uint4 v2 = *(const uint4*)&xl[(size_t)s2 * 64 + li * 8];
        uint4 v3 = *(const uint4*)&xl[(size_t)s3 * 64 + li * 8];
        wsum += w0 + w1 + w2 + w3;
        FMA8(v0, w0);
        FMA8(v1, w1);
        FMA8(v2, w2);
        FMA8(v3, w3);
    }
    // tail: 8 edges per iteration, masked
    const int last = end - 1;              // >= beg (self-loop guarantees >=1 edge)
    for (; k < end; k += 8) {
        const int i0 = k + sub;
        const int c0 = min(i0, last);
        const int s0 = (int)csr[c0];
        float w0 = lrelu_exp(a_s[(size_t)s0 * 2 + hh] + adh);
        if (i0 >= end) w0 = 0.f;
        uint4 v0 = *(const uint4*)&xl[(size_t)s0 * 64 + li * 8];
        wsum += w0;
        FMA8(v0, w0);
    }
    #pragma unroll
    for (int ofs = 8; ofs <= 32; ofs <<= 1) {
        wsum += __shfl_xor(wsum, ofs, 64);
        #pragma unroll
        for (int i = 0; i < 8; ++i) acc[i] += __shfl_xor(acc[i], ofs, 64);
    }
    if (sub == 0) {
        const float4 b1a = *(const float4*)&b1[li * 8];
        const float4 b1b = *(const float4*)&b1[li * 8 + 4];
        const float inv = 1.f / wsum;
        float h0 = elu_f(acc[0] * inv + b1a.x);
        float h1 = elu_f(acc[1] * inv + b1a.y);
        float h2 = elu_f(acc[2] * inv + b1a.z);
        float h3 = elu_f(acc[3] * inv + b1a.w);
        float h4 = elu_f(acc[4] * inv + b1b.x);
        float h5 = elu_f(acc[5] * inv + b1b.y);
        float h6 = elu_f(acc[6] * inv + b1b.z);
        float h7 = elu_f(acc[7] * inv + b1b.w);
        uint4 p;
        p.x = (unsigned)f2bf(h0) | ((unsigned)f2bf(h1) << 16);
        p.y = (unsigned)f2bf(h2) | ((unsigned)f2bf(h3) << 16);
        p.z = (unsigned)f2bf(h4) | ((unsigned)f2bf(h5) << 16);
        p.w = (unsigned)f2bf(h6) | ((unsigned)f2bf(h7) << 16);
        *(uint4*)&hout[(size_t)dst * 64 + li * 8] = p;
    }
}

// ---------------- GEMM2 via MFMA: xl2(fp8) = h @ W2, fused attention dots ----
__global__ __launch_bounds__(256) void k_gemm2m(
    const unsigned short* __restrict__ h, const float* __restrict__ W2,
    const float* __restrict__ att_s, const float* __restrict__ att_d,
    unsigned char* __restrict__ xl2, float* __restrict__ a_s, float* __restrict__ a_d)
{
    __shared__ unsigned short W2T[128][72];  // W2^T bf16, pad 72 (18.4 KB)
    __shared__ float psA[4][16], psD[4][16];
    const int t = threadIdx.x, wave = t >> 6, lane = t & 63;
    const int quad = lane >> 4, lm = lane & 15;
    for (int i = t; i < 64 * 128; i += 256)
        W2T[i & 127][i >> 7] = f2bf(W2[i]);  // W2T[c][k] = W2[k][c]
    __syncthreads();

    const int c0 = wave * 32 + lm;
    const int c1 = c0 + 16;
    bf16x8 bfr0[2], bfr1[2];
    #pragma unroll
    for (int s = 0; s < 2; ++s) {
        bfr0[s] = *(const bf16x8*)&W2T[c0][s * 32 + quad * 8];
        bfr1[s] = *(const bf16x8*)&W2T[c1][s * 32 + quad * 8];
    }
    const float as0 = att_s[c0], as1 = att_s[c1];
    const float ad0 = att_d[c0], ad1 = att_d[c1];

    const int r0 = blockIdx.x * 16;
    f32x4 acc0 = {0.f, 0.f, 0.f, 0.f}, acc1 = {0.f, 0.f, 0.f, 0.f};
    #pragma unroll
    for (int s = 0; s < 2; ++s) {
        bf16x8 afr = *(const bf16x8*)&h[(size_t)(r0 + lm) * 64 + s * 32 + quad * 8];
        acc0 = __builtin_amdgcn_mfma_f32_16x16x32_bf16(afr, bfr0[s], acc0, 0, 0, 0);
        acc1 = __builtin_amdgcn_mfma_f32_16x16x32_bf16(afr, bfr1[s], acc1, 0, 0, 0);
    }
    float psv[4], pdv[4];
    #pragma unroll
    for (int r = 0; r < 4; ++r) {
        float v0 = acc0[r], v1 = acc1[r];
        const size_t row = (size_t)(r0 + quad * 4 + r) * 128;
        xl2[row + c0] = f2fp8(v0);          // fp8 e4m3 gather table
        xl2[row + c1] = f2fp8(v1);
        psv[r] = v0 * as0 + v1 * as1;       // logits from fp32 (pre-quant)
        pdv[r] = v0 * ad0 + v1 * ad1;
    }
    #pragma unroll
    for (int ofs = 1; ofs <= 8; ofs <<= 1) {
        #pragma unroll
        for (int r = 0; r < 4; ++r) {
            psv[r] += __shfl_xor(psv[r], ofs, 64);
            pdv[r] += __shfl_xor(pdv[r], ofs, 64);
        }
    }
    if (lm == 0) {
        #pragma unroll
        for (int r = 0; r < 4; ++r) {
            psA[wave][quad * 4 + r] = psv[r];
            psD[wave][quad * 4 + r] = pdv[r];
        }
    }
    __syncthreads();
    if (t < 16) {
        a_s[r0 + t] = psA[0][t] + psA[1][t] + psA[2][t] + psA[3][t];
        a_d[r0 + t] = psD[0][t] + psD[1][t] + psD[2][t] + psD[3][t];
    }
}

// ------- layer-2 attention: inline weights, fp8 gather, bf16 out ------------
#define CFMA16(vv, ww) do { \
    f32x2 p_; \
    p_ = __builtin_amdgcn_cvt_pk_f32_fp8(vv.x, false); acc[0]  = fmaf(p_.x, ww, acc[0]);  acc[1]  = fmaf(p_.y, ww, acc[1]);  \
    p_ = __builtin_amdgcn_cvt_pk_f32_fp8(vv.x, true);  acc[2]  = fmaf(p_.x, ww, acc[2]);  acc[3]  = fmaf(p_.y, ww, acc[3]);  \
    p_ = __builtin_amdgcn_cvt_pk_f32_fp8(vv.y, false); acc[4]  = fmaf(p_.x, ww, acc[4]);  acc[5]  = fmaf(p_.y, ww, acc[5]);  \
    p_ = __builtin_amdgcn_cvt_pk_f32_fp8(vv.y, true);  acc[6]  = fmaf(p_.x, ww, acc[6]);  acc[7]  = fmaf(p_.y, ww, acc[7]);  \
    p_ = __builtin_amdgcn_cvt_pk_f32_fp8(vv.z, false); acc[8]  = fmaf(p_.x, ww, acc[8]);  acc[9]  = fmaf(p_.y, ww, acc[9]);  \
    p_ = __builtin_amdgcn_cvt_pk_f32_fp8(vv.z, true);  acc[10] = fmaf(p_.x, ww, acc[10]); acc[11] = fmaf(p_.y, ww, acc[11]); \
    p_ = __builtin_amdgcn_cvt_pk_f32_fp8(vv.w, false); acc[12] = fmaf(p_.x, ww, acc[12]); acc[13] = fmaf(p_.y, ww, acc[13]); \
    p_ = __builtin_amdgcn_cvt_pk_f32_fp8(vv.w, true);  acc[14] = fmaf(p_.x, ww, acc[14]); acc[15] = fmaf(p_.y, ww, acc[15]); \
} while (0)

__global__ __launch_bounds__(256) void k_attn2(
    const int* __restrict__ beg_a, const int* __restrict__ end_a,
    const unsigned* __restrict__ csr,
    const float* __restrict__ a_s, const float* __restrict__ a_d,
    const unsigned char* __restrict__ xl, unsigned short* __restrict__ out)
{
    const int wave = threadIdx.x >> 6, lane = threadIdx.x & 63;
    const int dst = blockIdx.x * 4 + wave;
    const int beg = beg_a[dst], end = end_a[dst];
    const int li = lane & 7, sub = lane >> 3;   // ch group li*16..+15; edge slot
    const float ad0 = a_d[dst];                 // wave-uniform

    float acc[16];
    #pragma unroll
    for (int i = 0; i < 16; ++i) acc[i] = 0.f;
    float wsum = 0.f;

    int k = beg;
    // main loop: all 32 slots valid, no masks, no clamps
    for (; k + 32 <= end; k += 32) {
        const int i0 = k + sub;
        const int s0 = (int)csr[i0];
        const int s1 = (int)csr[i0 + 8];
        const int s2 = (int)csr[i0 + 16];
        const int s3 = (int)csr[i0 + 24];
        const float w0 = lrelu_exp(a_s[s0] + ad0);
        const float w1 = lrelu_exp(a_s[s1] + ad0);
        const float w2 = lrelu_exp(a_s[s2] + ad0);
        const float w3 = lrelu_exp(a_s[s3] + ad0);
        uint4 v0 = *(const uint4*)&xl[(size_t)s0 * 128 + li * 16];
        uint4 v1 = *(const uint4*)&xl[(size_t)s1 * 128 + li * 16];
        uint4 v2 = *(const uint4*)&xl[(size_t)s2 * 128 + li * 16];
        uint4 v3 = *(const uint4*)&xl[(size_t)s3 * 128 + li * 16];
        wsum += w0 + w1 + w2 + w3;
        CFMA16(v0, w0);
        CFMA16(v1, w1);
        CFMA16(v2, w2);
        CFMA16(v3, w3);
    }
    // tail: 8 edges per iteration, masked
    const int last = end - 1;
    for (; k < end; k += 8) {
        const int i0 = k + sub;
        const int c0 = min(i0, last);
        const int s0 = (int)csr[c0];
        float w0 = lrelu_exp(a_s[s0] + ad0);
        if (i0 >= end) w0 = 0.f;
        uint4 v0 = *(const uint4*)&xl[(size_t)s0 * 128 + li * 16];
        wsum += w0;
        CFMA16(v0, w0);
    }
    #pragma unroll
    for (int ofs = 8; ofs <= 32; ofs <<= 1) {
        wsum += __shfl_xor(wsum, ofs, 64);
        #pragma unroll
        for (int i = 0; i < 16; ++i) acc[i] += __shfl_xor(acc[i], ofs, 64);
    }
    if (sub == 0) {
        const float inv = 1.f / wsum;
        unsigned short* op = &out[(size_t)dst * 128 + li * 16];
        uint4 pa, pb;
        pa.x = (unsigned)f2bf(acc[0]  * inv) | ((unsigned)f2bf(acc[1]  * inv) << 16);
        pa.y = (unsigned)f2bf(acc[2]  * inv) | ((unsigned)f2bf(acc[3]  * inv) << 16);
        pa.z = (unsigned)f2bf(acc[4]  * inv) | ((unsigned)f2bf(acc[5]  * inv) << 16);
        pa.w = (unsigned)f2bf(acc[6]  * inv) | ((unsigned)f2bf(acc[7]  * inv) << 16);
        pb.x = (unsigned)f2bf(acc[8]  * inv) | ((unsigned)f2bf(acc[9]  * inv) << 16);
        pb.y = (unsigned)f2bf(acc[10] * inv) | ((unsigned)f2bf(acc[11] * inv) << 16);
        pb.z = (unsigned)f2bf(acc[12] * inv) | ((unsigned)f2bf(acc[13] * inv) << 16);
        pb.w = (unsigned)f2bf(acc[14] * inv) | ((unsigned)f2bf(acc[15] * inv) << 16);
        *(uint4*)op       = pa;
        *(uint4*)(op + 8) = pb;
    }
}

// ---------------- pooling: 32 nodes/block, 2 node-lanes x 128 ch (bf16 in) ---
__global__ __launch_bounds__(256) void k_pool(
    const unsigned short* __restrict__ out2, const float* __restrict__ b2,
    const int* __restrict__ batch, float* __restrict__ sums, float* __restrict__ cnts)
{
    const int c    = threadIdx.x & 127;
    const int half = threadIdx.x >> 7;
    const int n0   = blockIdx.x * PN;
    const int nb   = n0 + half;
    if (nb >= N_NODES) return;
    const float bc = b2[c];
    float acc = 0.f;
    int cur = batch[nb], cnt = 0;
    for (int i = half; i < PN; i += 2) {
        int n = n0 + i;
        if (n >= N_NODES) break;
        int g = batch[n];
        if (g != cur) {
            atomicAdd(&sums[cur * OUT_CH + c], acc);
            if (c == 0) atomicAdd(&cnts[cur], (float)cnt);
            acc = 0.f; cnt = 0; cur = g;
        }
        float v = __uint_as_float((unsigned)out2[(size_t)n * OUT_CH + c] << 16);
        acc += elu_f(v + bc);
        cnt++;
    }
    if (cnt > 0) {
        atomicAdd(&sums[cur * OUT_CH + c], acc);
        if (c == 0) atomicAdd(&cnts[cur], (float)cnt);
    }
}

__global__ __launch_bounds__(256) void k_final(
    const float* __restrict__ sums, const float* __restrict__ cnts,
    float* __restrict__ out)
{
    int i = blockIdx.x * 256 + threadIdx.x;
    if (i >= N_GRAPHS * OUT_CH) return;
    out[i] = sums[i] / fmaxf(cnts[i >> 7], 1.f);
}

extern "C" void kernel_launch(void* const* d_in, const int* in_sizes, int n_in,
                              void* d_out, int out_size, void* d_ws, size_t ws_size,
                              hipStream_t stream)
{
    const float* x    = (const float*)d_in[0];
    const int*   ei   = (const int*)d_in[1];
    const int*   batch= (const int*)d_in[2];
    const float* W1   = (const float*)d_in[3];
    const float* as1  = (const float*)d_in[4];
    const float* ad1  = (const float*)d_in[5];
    const float* b1   = (const float*)d_in[6];
    const float* W2   = (const float*)d_in[7];
    const float* as2  = (const float*)d_in[8];
    const float* ad2  = (const float*)d_in[9];
    const float* b2   = (const float*)d_in[10];

    float* ws = (float*)d_ws;
    size_t o = 0;
    unsigned short* xl1b = (unsigned short*)(ws + o); o += (size_t)N_NODES * C1 / 2;
    unsigned short* hbuf = (unsigned short*)(ws + o); o += (size_t)N_NODES * C1 / 2;
    unsigned char*  xl2q = (unsigned char*)(ws + o);  o += (size_t)N_NODES * OUT_CH / 4;
    float*    a_s1 = ws + o; o += (size_t)N_NODES * 2;
    float*    a_d1 = ws + o; o += (size_t)N_NODES * 2;
    float*    a_s2 = ws + o; o += (size_t)N_NODES;
    float*    a_d2 = ws + o; o += (size_t)N_NODES;
    unsigned short* out2b = (unsigned short*)(ws + o); o += (size_t)N_NODES * OUT_CH / 2;
    unsigned* bbuf = (unsigned*)(ws + o); o += (size_t)NBUCK * BCAP;
    int*      beg  = (int*)(ws + o); o += (size_t)N_NODES;
    int*      end  = (int*)(ws + o); o += (size_t)N_NODES;
    size_t zero_start = o;
    int*      gcur = (int*)(ws + o); o += (size_t)NBUCK;
    float*    sums = ws + o;         o += (size_t)N_GRAPHS * OUT_CH;
    float*    cnts = ws + o;         o += (size_t)N_GRAPHS;
    size_t zero_bytes = (o - zero_start) * sizeof(float);
    hipMemsetAsync(ws + zero_start, 0, zero_bytes, stream);

    const int nchunks = (E_TOT + CHUNK - 1) / CHUNK;   // 202

    k_gemm1<<<N_NODES / 16, 256, 0, stream>>>(x, W1, as1, ad1, xl1b, a_s1, a_d1);
    k_bin<<<nchunks, 256, 0, stream>>>(ei, gcur, bbuf);
    k_bsort<<<NBUCK, 256, 0, stream>>>(gcur, bbuf, beg, end);
    k_attn1<<<N_NODES / 4, 256, 0, stream>>>(beg, end, bbuf, a_s1, a_d1, xl1b, b1, hbuf);
    k_gemm2m<<<(N_NODES + 15) / 16, 256, 0, stream>>>(hbuf, W2, as2, ad2, xl2q, a_s2, a_d2);
    k_attn2<<<N_NODES / 4, 256, 0, stream>>>(beg, end, bbuf, a_s2, a_d2, xl2q, out2b);
    k_pool<<<(N_NODES + PN - 1) / PN, 256, 0, stream>>>(out2b, b2, batch, sums, cnts);
    k_final<<<(N_GRAPHS * OUT_CH + 255) / 256, 256, 0, stream>>>(sums, cnts, (float*)d_out);
}

// Round 9
// 257.562 us; speedup vs baseline: 1.1082x; 1.0139x over previous
//
#include <hip/hip_runtime.h>

#define N_NODES 50000
#define N_EDGES 1600000
#define E_TOT   (N_EDGES + N_NODES)   // 1,650,000 incl. self-loops
#define IN_CH   128
#define C1      64                    // heads(2) * hid(32)
#define OUT_CH  128
#define N_GRAPHS 64
#define NEG_SLOPE 0.2f

#define BSH   7                        // 128 dsts per bucket
#define NBUCK ((N_NODES + 127) / 128)  // 391
#define BCAP  5120                     // per-bucket region cap (mean 4220, ~14 sigma)
#define CHUNK 8192                     // edges per k_bin workgroup
#define PN    32                       // nodes per k_pool block

typedef __attribute__((ext_vector_type(8))) short bf16x8;
typedef __attribute__((ext_vector_type(4))) float f32x4;
typedef __attribute__((ext_vector_type(2))) float f32x2;

__device__ __forceinline__ float elu_f(float v) {
    return v > 0.f ? v : (__expf(v) - 1.f);
}
__device__ __forceinline__ unsigned short f2bf(float f) {   // RNE
    unsigned u = __float_as_uint(f);
    return (unsigned short)((u + 0x7FFFu + ((u >> 16) & 1u)) >> 16);
}
__device__ __forceinline__ float bf_lo(unsigned u) { return __uint_as_float(u << 16); }
__device__ __forceinline__ float bf_hi(unsigned u) { return __uint_as_float(u & 0xFFFF0000u); }
__device__ __forceinline__ unsigned char f2fp8(float v) {   // OCP e4m3 via HW cvt
    return (unsigned char)(__builtin_amdgcn_cvt_pk_fp8_f32(v, v, 0, false) & 0xFF);
}
__device__ __forceinline__ float lrelu_exp(float e) {
    e = e > 0.f ? e : NEG_SLOPE * e;
    return __expf(e);
}

// ---------------- GEMM1 via MFMA: xl1(bf16) = x @ W1, fused attention dots ---
__global__ __launch_bounds__(256) void k_gemm1(
    const float* __restrict__ x, const float* __restrict__ W1,
    const float* __restrict__ att_s, const float* __restrict__ att_d,
    unsigned short* __restrict__ xl1, float* __restrict__ a_s, float* __restrict__ a_d)
{
    __shared__ unsigned short W1T[64][136];  // W1^T bf16, +8 pad (17.4 KB)
    __shared__ float psA[4][16], psD[4][16];
    const int t = threadIdx.x, wave = t >> 6, lane = t & 63;
    const int quad = lane >> 4, lm = lane & 15;
    for (int i = t; i < 128 * 64; i += 256)
        W1T[i & 63][i >> 6] = f2bf(W1[i]);   // W1T[c][k] = W1[k][c]
    __syncthreads();

    const int n0 = wave * 16;
    const int c  = n0 + lm;                  // this lane's output column
    bf16x8 bfr[4];
    #pragma unroll
    for (int s = 0; s < 4; ++s)
        bfr[s] = *(const bf16x8*)&W1T[c][s * 32 + quad * 8];
    const float asc = att_s[c], adc = att_d[c];

    const int r0 = blockIdx.x * 16;
    f32x4 acc = {0.f, 0.f, 0.f, 0.f};
    #pragma unroll
    for (int s = 0; s < 4; ++s) {
        const float* xp = &x[(size_t)(r0 + lm) * 128 + s * 32 + quad * 8];
        float4 xa = *(const float4*)xp;
        float4 xb = *(const float4*)(xp + 4);
        bf16x8 afr;
        afr[0] = (short)f2bf(xa.x); afr[1] = (short)f2bf(xa.y);
        afr[2] = (short)f2bf(xa.z); afr[3] = (short)f2bf(xa.w);
        afr[4] = (short)f2bf(xb.x); afr[5] = (short)f2bf(xb.y);
        afr[6] = (short)f2bf(xb.z); afr[7] = (short)f2bf(xb.w);
        acc = __builtin_amdgcn_mfma_f32_16x16x32_bf16(afr, bfr[s], acc, 0, 0, 0);
    }
    float psv[4], pdv[4];
    #pragma unroll
    for (int r = 0; r < 4; ++r) {
        float v = acc[r];
        xl1[(size_t)(r0 + quad * 4 + r) * 64 + c] = f2bf(v);
        psv[r] = v * asc;
        pdv[r] = v * adc;
    }
    #pragma unroll
    for (int ofs = 1; ofs <= 8; ofs <<= 1) {
        #pragma unroll
        for (int r = 0; r < 4; ++r) {
            psv[r] += __shfl_xor(psv[r], ofs, 64);
            pdv[r] += __shfl_xor(pdv[r], ofs, 64);
        }
    }
    if (lm == 0) {
        #pragma unroll
        for (int r = 0; r < 4; ++r) {
            psA[wave][quad * 4 + r] = psv[r];
            psD[wave][quad * 4 + r] = pdv[r];
        }
    }
    __syncthreads();
    if (t < 32) {
        const int row = t & 15, h = t >> 4;
        a_s[(size_t)(r0 + row) * 2 + h] = psA[2 * h][row] + psA[2 * h + 1][row];
        a_d[(size_t)(r0 + row) * 2 + h] = psD[2 * h][row] + psD[2 * h + 1][row];
    }
}

// ---------------- pass 1: LDS-staged binning by dst>>7 ----------------------
__global__ __launch_bounds__(256) void k_bin(
    const int* __restrict__ ei, int* __restrict__ gcur, unsigned* __restrict__ bbuf)
{
    __shared__ int cnt[512];
    __shared__ int base[NBUCK];
    __shared__ int cnt2[NBUCK];
    __shared__ int gpos[NBUCK];
    __shared__ unsigned stage[CHUNK];      // 32 KB
    __shared__ unsigned short bof[CHUNK];  // 16 KB
    const int t = threadIdx.x;
    const long long e0 = (long long)blockIdx.x * CHUNK;
    const int nE = (int)min((long long)CHUNK, (long long)E_TOT - e0);

    cnt[t] = 0; cnt[t + 256] = 0;
    for (int b = t; b < NBUCK; b += 256) cnt2[b] = 0;
    __syncthreads();

    const int per = CHUNK / 256;           // 32
    int myb[per]; unsigned mye[per];
    #pragma unroll
    for (int i = 0; i < per; ++i) {
        int idx = t + 256 * i;
        myb[i] = -1;
        if (idx < nE) {
            long long e = e0 + idx;
            int s, d;
            if (e < N_EDGES) { s = ei[e]; d = ei[N_EDGES + e]; }
            else             { s = d = (int)(e - N_EDGES); }
            myb[i] = d >> BSH;
            mye[i] = ((unsigned)(d & 127) << 17) | (unsigned)s;
            atomicAdd(&cnt[myb[i]], 1);
        }
    }
    __syncthreads();
    for (int ofs = 1; ofs < 512; ofs <<= 1) {
        int v0 = (t >= ofs) ? cnt[t - ofs] : 0;
        int v1 = cnt[t + 256 - ofs];
        __syncthreads();
        cnt[t] += v0; cnt[t + 256] += v1;
        __syncthreads();
    }
    for (int b = t; b < NBUCK; b += 256) {
        base[b] = (b == 0) ? 0 : cnt[b - 1];
        int c = cnt[b] - base[b];
        gpos[b] = (c > 0) ? atomicAdd(&gcur[b], c) : 0;
    }
    __syncthreads();
    #pragma unroll
    for (int i = 0; i < per; ++i) {
        if (myb[i] >= 0) {
            int slot = base[myb[i]] + atomicAdd(&cnt2[myb[i]], 1);
            stage[slot] = mye[i];
            bof[slot] = (unsigned short)myb[i];
        }
    }
    __syncthreads();
    for (int i = t; i < nE; i += 256) {
        int b = bof[i];
        int pos = gpos[b] + (i - base[b]);
        if (pos < BCAP)
            bbuf[(size_t)b * BCAP + pos] = stage[i];
    }
}

// -------- pass 2: per-bucket counting sort, emits beg/end (light version) ---
__global__ __launch_bounds__(256) void k_bsort(
    const int* __restrict__ gcur, unsigned* __restrict__ bbuf,
    int* __restrict__ beg, int* __restrict__ end)
{
    __shared__ unsigned est[BCAP];   // 20 KB
    __shared__ unsigned sst[BCAP];   // 20 KB
    __shared__ int c[128], lbase[128], c2[128];
    const int b = blockIdx.x, t = threadIdx.x;
    const int n = min(gcur[b], BCAP);
    unsigned* reg = bbuf + (size_t)b * BCAP;
    for (int i = t; i < n; i += 256) est[i] = reg[i];
    if (t < 128) { c[t] = 0; c2[t] = 0; }
    __syncthreads();
    for (int i = t; i < n; i += 256) atomicAdd(&c[est[i] >> 17], 1);
    __syncthreads();
    for (int ofs = 1; ofs < 128; ofs <<= 1) {
        int v = (t < 128 && t >= ofs) ? c[t - ofs] : 0;
        __syncthreads();
        if (t < 128) c[t] += v;
        __syncthreads();
    }
    if (t < 128) {
        lbase[t] = (t == 0) ? 0 : c[t - 1];
        int dst = (b << BSH) + t;
        if (dst < N_NODES) {
            beg[dst] = b * BCAP + lbase[t];
            end[dst] = b * BCAP + c[t];
        }
    }
    __syncthreads();
    for (int i = t; i < n; i += 256) {
        unsigned v = est[i];
        int dl = (int)(v >> 17);
        int pos = lbase[dl] + atomicAdd(&c2[dl], 1);
        sst[pos] = v & 0x1FFFFu;             // strip dl bits -> pure src index
    }
    __syncthreads();
    for (int i = t; i < n; i += 256) reg[i] = sst[i];
}

// ------- layer-1 attention: 128-thr blocks (2 dsts), inline weights ---------
#define FMA8(vv, ww) do { \
    acc[0] = fmaf(bf_lo(vv.x), ww, acc[0]); acc[1] = fmaf(bf_hi(vv.x), ww, acc[1]); \
    acc[2] = fmaf(bf_lo(vv.y), ww, acc[2]); acc[3] = fmaf(bf_hi(vv.y), ww, acc[3]); \
    acc[4] = fmaf(bf_lo(vv.z), ww, acc[4]); acc[5] = fmaf(bf_hi(vv.z), ww, acc[5]); \
    acc[6] = fmaf(bf_lo(vv.w), ww, acc[6]); acc[7] = fmaf(bf_hi(vv.w), ww, acc[7]); \
} while (0)

__global__ __launch_bounds__(128) void k_attn1(
    const int* __restrict__ beg_a, const int* __restrict__ end_a,
    const unsigned* __restrict__ csr,
    const float* __restrict__ a_s, const float* __restrict__ a_d,
    const unsigned short* __restrict__ xl, const float* __restrict__ b1,
    unsigned short* __restrict__ hout)    // [N][64] bf16: elu(aggregate + b1)
{
    const int wave = threadIdx.x >> 6, lane = threadIdx.x & 63;
    const int dst = blockIdx.x * 2 + wave;
    const int beg = beg_a[dst], end = end_a[dst];
    const int li = lane & 7, sub = lane >> 3, hh = li >> 2;
    const float adh = a_d[(size_t)dst * 2 + hh];   // wave-uniform per head

    float acc[8];
    #pragma unroll
    for (int i = 0; i < 8; ++i) acc[i] = 0.f;
    float wsum = 0.f;

    int k = beg;
    // main loop: all 32 slots valid, no masks, no clamps
    for (; k + 32 <= end; k += 32) {
        const int i0 = k + sub;
        const int s0 = (int)csr[i0];
        const int s1 = (int)csr[i0 + 8];
        const int s2 = (int)csr[i0 + 16];
        const int s3 = (int)csr[i0 + 24];
        const float w0 = lrelu_exp(a_s[(size_t)s0 * 2 + hh] + adh);
        const float w1 = lrelu_exp(a_s[(size_t)s1 * 2 + hh] + adh);
        const float w2 = lrelu_exp(a_s[(size_t)s2 * 2 + hh] + adh);
        const float w3 = lrelu_exp(a_s[(size_t)s3 * 2 + hh] + adh);
        uint4 v0 = *(const uint4*)&xl[(size_t)s0 * 64 + li * 8];
        uint4 v1 = *(const uint4*)&xl[(size_t)s1 * 64 + li * 8];
        uint4 v2 = *(const uint4*)&xl[(size_t)s2 * 64 + li * 8];
        uint4 v3 = *(const uint4*)&xl[(size_t)s3 * 64 + li * 8];
        wsum += w0 + w1 + w2 + w3;
        FMA8(v0, w0);
        FMA8(v1, w1);
        FMA8(v2, w2);
        FMA8(v3, w3);
    }
    // tail: 8 edges per iteration, masked
    const int last = end - 1;              // >= beg (self-loop guarantees >=1 edge)
    for (; k < end; k += 8) {
        const int i0 = k + sub;
        const int c0 = min(i0, last);
        const int s0 = (int)csr[c0];
        float w0 = lrelu_exp(a_s[(size_t)s0 * 2 + hh] + adh);
        if (i0 >= end) w0 = 0.f;
        uint4 v0 = *(const uint4*)&xl[(size_t)s0 * 64 + li * 8];
        wsum += w0;
        FMA8(v0, w0);
    }
    #pragma unroll
    for (int ofs = 8; ofs <= 32; ofs <<= 1) {
        wsum += __shfl_xor(wsum, ofs, 64);
        #pragma unroll
        for (int i = 0; i < 8; ++i) acc[i] += __shfl_xor(acc[i], ofs, 64);
    }
    if (sub == 0) {
        const float4 b1a = *(const float4*)&b1[li * 8];
        const float4 b1b = *(const float4*)&b1[li * 8 + 4];
        const float inv = 1.f / wsum;
        float h0 = elu_f(acc[0] * inv + b1a.x);
        float h1 = elu_f(acc[1] * inv + b1a.y);
        float h2 = elu_f(acc[2] * inv + b1a.z);
        float h3 = elu_f(acc[3] * inv + b1a.w);
        float h4 = elu_f(acc[4] * inv + b1b.x);
        float h5 = elu_f(acc[5] * inv + b1b.y);
        float h6 = elu_f(acc[6] * inv + b1b.z);
        float h7 = elu_f(acc[7] * inv + b1b.w);
        uint4 p;
        p.x = (unsigned)f2bf(h0) | ((unsigned)f2bf(h1) << 16);
        p.y = (unsigned)f2bf(h2) | ((unsigned)f2bf(h3) << 16);
        p.z = (unsigned)f2bf(h4) | ((unsigned)f2bf(h5) << 16);
        p.w = (unsigned)f2bf(h6) | ((unsigned)f2bf(h7) << 16);
        *(uint4*)&hout[(size_t)dst * 64 + li * 8] = p;
    }
}

// ---------------- GEMM2 via MFMA: xl2(fp8) = h @ W2, fused attention dots ----
__global__ __launch_bounds__(256) void k_gemm2m(
    const unsigned short* __restrict__ h, const float* __restrict__ W2,
    const float* __restrict__ att_s, const float* __restrict__ att_d,
    unsigned char* __restrict__ xl2, float* __restrict__ a_s, float* __restrict__ a_d)
{
    __shared__ unsigned short W2T[128][72];  // W2^T bf16, pad 72 (18.4 KB)
    __shared__ float psA[4][16], psD[4][16];
    const int t = threadIdx.x, wave = t >> 6, lane = t & 63;
    const int quad = lane >> 4, lm = lane & 15;
    for (int i = t; i < 64 * 128; i += 256)
        W2T[i & 127][i >> 7] = f2bf(W2[i]);  // W2T[c][k] = W2[k][c]
    __syncthreads();

    const int c0 = wave * 32 + lm;
    const int c1 = c0 + 16;
    bf16x8 bfr0[2], bfr1[2];
    #pragma unroll
    for (int s = 0; s < 2; ++s) {
        bfr0[s] = *(const bf16x8*)&W2T[c0][s * 32 + quad * 8];
        bfr1[s] = *(const bf16x8*)&W2T[c1][s * 32 + quad * 8];
    }
    const float as0 = att_s[c0], as1 = att_s[c1];
    const float ad0 = att_d[c0], ad1 = att_d[c1];

    const int r0 = blockIdx.x * 16;
    f32x4 acc0 = {0.f, 0.f, 0.f, 0.f}, acc1 = {0.f, 0.f, 0.f, 0.f};
    #pragma unroll
    for (int s = 0; s < 2; ++s) {
        bf16x8 afr = *(const bf16x8*)&h[(size_t)(r0 + lm) * 64 + s * 32 + quad * 8];
        acc0 = __builtin_amdgcn_mfma_f32_16x16x32_bf16(afr, bfr0[s], acc0, 0, 0, 0);
        acc1 = __builtin_amdgcn_mfma_f32_16x16x32_bf16(afr, bfr1[s], acc1, 0, 0, 0);
    }
    float psv[4], pdv[4];
    #pragma unroll
    for (int r = 0; r < 4; ++r) {
        float v0 = acc0[r], v1 = acc1[r];
        const size_t row = (size_t)(r0 + quad * 4 + r) * 128;
        xl2[row + c0] = f2fp8(v0);          // fp8 e4m3 gather table
        xl2[row + c1] = f2fp8(v1);
        psv[r] = v0 * as0 + v1 * as1;       // logits from fp32 (pre-quant)
        pdv[r] = v0 * ad0 + v1 * ad1;
    }
    #pragma unroll
    for (int ofs = 1; ofs <= 8; ofs <<= 1) {
        #pragma unroll
        for (int r = 0; r < 4; ++r) {
            psv[r] += __shfl_xor(psv[r], ofs, 64);
            pdv[r] += __shfl_xor(pdv[r], ofs, 64);
        }
    }
    if (lm == 0) {
        #pragma unroll
        for (int r = 0; r < 4; ++r) {
            psA[wave][quad * 4 + r] = psv[r];
            psD[wave][quad * 4 + r] = pdv[r];
        }
    }
    __syncthreads();
    if (t < 16) {
        a_s[r0 + t] = psA[0][t] + psA[1][t] + psA[2][t] + psA[3][t];
        a_d[r0 + t] = psD[0][t] + psD[1][t] + psD[2][t] + psD[3][t];
    }
}

// ------- layer-2 attention: 128-thr blocks (2 dsts), fp8 gather, bf16 out ---
#define CFMA16(vv, ww) do { \
    f32x2 p_; \
    p_ = __builtin_amdgcn_cvt_pk_f32_fp8(vv.x, false); acc[0]  = fmaf(p_.x, ww, acc[0]);  acc[1]  = fmaf(p_.y, ww, acc[1]);  \
    p_ = __builtin_amdgcn_cvt_pk_f32_fp8(vv.x, true);  acc[2]  = fmaf(p_.x, ww, acc[2]);  acc[3]  = fmaf(p_.y, ww, acc[3]);  \
    p_ = __builtin_amdgcn_cvt_pk_f32_fp8(vv.y, false); acc[4]  = fmaf(p_.x, ww, acc[4]);  acc[5]  = fmaf(p_.y, ww, acc[5]);  \
    p_ = __builtin_amdgcn_cvt_pk_f32_fp8(vv.y, true);  acc[6]  = fmaf(p_.x, ww, acc[6]);  acc[7]  = fmaf(p_.y, ww, acc[7]);  \
    p_ = __builtin_amdgcn_cvt_pk_f32_fp8(vv.z, false); acc[8]  = fmaf(p_.x, ww, acc[8]);  acc[9]  = fmaf(p_.y, ww, acc[9]);  \
    p_ = __builtin_amdgcn_cvt_pk_f32_fp8(vv.z, true);  acc[10] = fmaf(p_.x, ww, acc[10]); acc[11] = fmaf(p_.y, ww, acc[11]); \
    p_ = __builtin_amdgcn_cvt_pk_f32_fp8(vv.w, false); acc[12] = fmaf(p_.x, ww, acc[12]); acc[13] = fmaf(p_.y, ww, acc[13]); \
    p_ = __builtin_amdgcn_cvt_pk_f32_fp8(vv.w, true);  acc[14] = fmaf(p_.x, ww, acc[14]); acc[15] = fmaf(p_.y, ww, acc[15]); \
} while (0)

__global__ __launch_bounds__(128) void k_attn2(
    const int* __restrict__ beg_a, const int* __restrict__ end_a,
    const unsigned* __restrict__ csr,
    const float* __restrict__ a_s, const float* __restrict__ a_d,
    const unsigned char* __restrict__ xl, unsigned short* __restrict__ out)
{
    const int wave = threadIdx.x >> 6, lane = threadIdx.x & 63;
    const int dst = blockIdx.x * 2 + wave;
    const int beg = beg_a[dst], end = end_a[dst];
    const int li = lane & 7, sub = lane >> 3;   // ch group li*16..+15; edge slot
    const float ad0 = a_d[dst];                 // wave-uniform

    float acc[16];
    #pragma unroll
    for (int i = 0; i < 16; ++i) acc[i] = 0.f;
    float wsum = 0.f;

    int k = beg;
    // main loop: all 32 slots valid, no masks, no clamps
    for (; k + 32 <= end; k += 32) {
        const int i0 = k + sub;
        const int s0 = (int)csr[i0];
        const int s1 = (int)csr[i0 + 8];
        const int s2 = (int)csr[i0 + 16];
        const int s3 = (int)csr[i0 + 24];
        const float w0 = lrelu_exp(a_s[s0] + ad0);
        const float w1 = lrelu_exp(a_s[s1] + ad0);
        const float w2 = lrelu_exp(a_s[s2] + ad0);
        const float w3 = lrelu_exp(a_s[s3] + ad0);
        uint4 v0 = *(const uint4*)&xl[(size_t)s0 * 128 + li * 16];
        uint4 v1 = *(const uint4*)&xl[(size_t)s1 * 128 + li * 16];
        uint4 v2 = *(const uint4*)&xl[(size_t)s2 * 128 + li * 16];
        uint4 v3 = *(const uint4*)&xl[(size_t)s3 * 128 + li * 16];
        wsum += w0 + w1 + w2 + w3;
        CFMA16(v0, w0);
        CFMA16(v1, w1);
        CFMA16(v2, w2);
        CFMA16(v3, w3);
    }
    // tail: 8 edges per iteration, masked
    const int last = end - 1;
    for (; k < end; k += 8) {
        const int i0 = k + sub;
        const int c0 = min(i0, last);
        const int s0 = (int)csr[c0];
        float w0 = lrelu_exp(a_s[s0] + ad0);
        if (i0 >= end) w0 = 0.f;
        uint4 v0 = *(const uint4*)&xl[(size_t)s0 * 128 + li * 16];
        wsum += w0;
        CFMA16(v0, w0);
    }
    #pragma unroll
    for (int ofs = 8; ofs <= 32; ofs <<= 1) {
        wsum += __shfl_xor(wsum, ofs, 64);
        #pragma unroll
        for (int i = 0; i < 16; ++i) acc[i] += __shfl_xor(acc[i], ofs, 64);
    }
    if (sub == 0) {
        const float inv = 1.f / wsum;
        unsigned short* op = &out[(size_t)dst * 128 + li * 16];
        uint4 pa, pb;
        pa.x = (unsigned)f2bf(acc[0]  * inv) | ((unsigned)f2bf(acc[1]  * inv) << 16);
        pa.y = (unsigned)f2bf(acc[2]  * inv) | ((unsigned)f2bf(acc[3]  * inv) << 16);
        pa.z = (unsigned)f2bf(acc[4]  * inv) | ((unsigned)f2bf(acc[5]  * inv) << 16);
        pa.w = (unsigned)f2bf(acc[6]  * inv) | ((unsigned)f2bf(acc[7]  * inv) << 16);
        pb.x = (unsigned)f2bf(acc[8]  * inv) | ((unsigned)f2bf(acc[9]  * inv) << 16);
        pb.y = (unsigned)f2bf(acc[10] * inv) | ((unsigned)f2bf(acc[11] * inv) << 16);
        pb.z = (unsigned)f2bf(acc[12] * inv) | ((unsigned)f2bf(acc[13] * inv) << 16);
        pb.w = (unsigned)f2bf(acc[14] * inv) | ((unsigned)f2bf(acc[15] * inv) << 16);
        *(uint4*)op       = pa;
        *(uint4*)(op + 8) = pb;
    }
}

// ---------------- pooling: 32 nodes/block, 2 node-lanes x 128 ch (bf16 in) ---
__global__ __launch_bounds__(256) void k_pool(
    const unsigned short* __restrict__ out2, const float* __restrict__ b2,
    const int* __restrict__ batch, float* __restrict__ sums, float* __restrict__ cnts)
{
    const int c    = threadIdx.x & 127;
    const int half = threadIdx.x >> 7;
    const int n0   = blockIdx.x * PN;
    const int nb   = n0 + half;
    if (nb >= N_NODES) return;
    const float bc = b2[c];
    float acc = 0.f;
    int cur = batch[nb], cnt = 0;
    for (int i = half; i < PN; i += 2) {
        int n = n0 + i;
        if (n >= N_NODES) break;
        int g = batch[n];
        if (g != cur) {
            atomicAdd(&sums[cur * OUT_CH + c], acc);
            if (c == 0) atomicAdd(&cnts[cur], (float)cnt);
            acc = 0.f; cnt = 0; cur = g;
        }
        float v = __uint_as_float((unsigned)out2[(size_t)n * OUT_CH + c] << 16);
        acc += elu_f(v + bc);
        cnt++;
    }
    if (cnt > 0) {
        atomicAdd(&sums[cur * OUT_CH + c], acc);
        if (c == 0) atomicAdd(&cnts[cur], (float)cnt);
    }
}

__global__ __launch_bounds__(256) void k_final(
    const float* __restrict__ sums, const float* __restrict__ cnts,
    float* __restrict__ out)
{
    int i = blockIdx.x * 256 + threadIdx.x;
    if (i >= N_GRAPHS * OUT_CH) return;
    out[i] = sums[i] / fmaxf(cnts[i >> 7], 1.f);
}

extern "C" void kernel_launch(void* const* d_in, const int* in_sizes, int n_in,
                              void* d_out, int out_size, void* d_ws, size_t ws_size,
                              hipStream_t stream)
{
    const float* x    = (const float*)d_in[0];
    const int*   ei   = (const int*)d_in[1];
    const int*   batch= (const int*)d_in[2];
    const float* W1   = (const float*)d_in[3];
    const float* as1  = (const float*)d_in[4];
    const float* ad1  = (const float*)d_in[5];
    const float* b1   = (const float*)d_in[6];
    const float* W2   = (const float*)d_in[7];
    const float* as2  = (const float*)d_in[8];
    const float* ad2  = (const float*)d_in[9];
    const float* b2   = (const float*)d_in[10];

    float* ws = (float*)d_ws;
    size_t o = 0;
    unsigned short* xl1b = (unsigned short*)(ws + o); o += (size_t)N_NODES * C1 / 2;
    unsigned short* hbuf = (unsigned short*)(ws + o); o += (size_t)N_NODES * C1 / 2;
    unsigned char*  xl2q = (unsigned char*)(ws + o);  o += (size_t)N_NODES * OUT_CH / 4;
    float*    a_s1 = ws + o; o += (size_t)N_NODES * 2;
    float*    a_d1 = ws + o; o += (size_t)N_NODES * 2;
    float*    a_s2 = ws + o; o += (size_t)N_NODES;
    float*    a_d2 = ws + o; o += (size_t)N_NODES;
    unsigned short* out2b = (unsigned short*)(ws + o); o += (size_t)N_NODES * OUT_CH / 2;
    unsigned* bbuf = (unsigned*)(ws + o); o += (size_t)NBUCK * BCAP;
    int*      beg  = (int*)(ws + o); o += (size_t)N_NODES;
    int*      end  = (int*)(ws + o); o += (size_t)N_NODES;
    size_t zero_start = o;
    int*      gcur = (int*)(ws + o); o += (size_t)NBUCK;
    float*    sums = ws + o;         o += (size_t)N_GRAPHS * OUT_CH;
    float*    cnts = ws + o;         o += (size_t)N_GRAPHS;
    size_t zero_bytes = (o - zero_start) * sizeof(float);
    hipMemsetAsync(ws + zero_start, 0, zero_bytes, stream);

    const int nchunks = (E_TOT + CHUNK - 1) / CHUNK;   // 202

    k_gemm1<<<N_NODES / 16, 256, 0, stream>>>(x, W1, as1, ad1, xl1b, a_s1, a_d1);
    k_bin<<<nchunks, 256, 0, stream>>>(ei, gcur, bbuf);
    k_bsort<<<NBUCK, 256, 0, stream>>>(gcur, bbuf, beg, end);
    k_attn1<<<N_NODES / 2, 128, 0, stream>>>(beg, end, bbuf, a_s1, a_d1, xl1b, b1, hbuf);
    k_gemm2m<<<(N_NODES + 15) / 16, 256, 0, stream>>>(hbuf, W2, as2, ad2, xl2q, a_s2, a_d2);
    k_attn2<<<N_NODES / 2, 128, 0, stream>>>(beg, end, bbuf, a_s2, a_d2, xl2q, out2b);
    k_pool<<<(N_NODES + PN - 1) / PN, 256, 0, stream>>>(out2b, b2, batch, sums, cnts);
    k_final<<<(N_GRAPHS * OUT_CH + 255) / 256, 256, 0, stream>>>(sums, cnts, (float*)d_out);
}

// Round 10
// 250.252 us; speedup vs baseline: 1.1405x; 1.0292x over previous
//
#include <hip/hip_runtime.h>

#define N_NODES 50000
#define N_EDGES 1600000
#define E_TOT   (N_EDGES + N_NODES)   // 1,650,000 incl. self-loops
#define IN_CH   128
#define C1      64                    // heads(2) * hid(32)
#define OUT_CH  128
#define N_GRAPHS 64
#define NEG_SLOPE 0.2f

#define BSH   7                        // 128 dsts per bucket
#define NBUCK ((N_NODES + 127) / 128)  // 391
#define BCAP  5120                     // per-bucket region cap (mean 4220, ~14 sigma)
#define CHUNK 8192                     // edges per k_bin workgroup
#define NCHUNKS ((E_TOT + CHUNK - 1) / CHUNK)   // 202
#define PN    32                       // nodes per k_pool block

typedef __attribute__((ext_vector_type(8))) short bf16x8;
typedef __attribute__((ext_vector_type(4))) float f32x4;
typedef __attribute__((ext_vector_type(2))) float f32x2;

__device__ __forceinline__ float elu_f(float v) {
    return v > 0.f ? v : (__expf(v) - 1.f);
}
__device__ __forceinline__ unsigned short f2bf(float f) {   // RNE
    unsigned u = __float_as_uint(f);
    return (unsigned short)((u + 0x7FFFu + ((u >> 16) & 1u)) >> 16);
}
__device__ __forceinline__ float bf_lo(unsigned u) { return __uint_as_float(u << 16); }
__device__ __forceinline__ float bf_hi(unsigned u) { return __uint_as_float(u & 0xFFFF0000u); }
__device__ __forceinline__ unsigned char f2fp8(float v) {   // OCP e4m3 via HW cvt
    return (unsigned char)(__builtin_amdgcn_cvt_pk_fp8_f32(v, v, 0, false) & 0xFF);
}
__device__ __forceinline__ float lrelu_exp(float e) {
    e = e > 0.f ? e : NEG_SLOPE * e;
    return __expf(e);
}

// ---- fused: blocks [0,NCHUNKS) = edge binning; blocks [NCHUNKS,..) = GEMM1 --
// The two bodies are fully independent (bin: ei -> bbuf/gcur; gemm1: x,W1 ->
// xl1/a_s/a_d). One dispatch lets them co-execute on the device, converting
// serial sum into max. Shared memory aliased via one byte array (union).
__global__ __launch_bounds__(256) void k_g1bin(
    const float* __restrict__ x, const float* __restrict__ W1,
    const float* __restrict__ att_s, const float* __restrict__ att_d,
    unsigned short* __restrict__ xl1, float* __restrict__ a_s, float* __restrict__ a_d,
    const int* __restrict__ ei, int* __restrict__ gcur, unsigned* __restrict__ bbuf)
{
    __shared__ __align__(16) char smem[55904];   // bin: 55.9 KB; gemm1: 17.9 KB
    const int t = threadIdx.x;

    if (blockIdx.x < NCHUNKS) {
        // ---------------- bin path (LDS-staged binning by dst>>7) ----------
        int* cnt  = (int*)smem;                       // 512 ints
        int* base = (int*)(smem + 2048);              // NBUCK
        int* cnt2 = (int*)(smem + 3612);              // NBUCK
        int* gpos = (int*)(smem + 5176);              // NBUCK
        unsigned* stage = (unsigned*)(smem + 6740);   // CHUNK (32 KB)
        unsigned short* bof = (unsigned short*)(smem + 39508);  // CHUNK (16 KB)

        const long long e0 = (long long)blockIdx.x * CHUNK;
        const int nE = (int)min((long long)CHUNK, (long long)E_TOT - e0);

        cnt[t] = 0; cnt[t + 256] = 0;
        for (int b = t; b < NBUCK; b += 256) cnt2[b] = 0;
        __syncthreads();

        const int per = CHUNK / 256;           // 32
        int myb[per]; unsigned mye[per];
        #pragma unroll
        for (int i = 0; i < per; ++i) {
            int idx = t + 256 * i;
            myb[i] = -1;
            if (idx < nE) {
                long long e = e0 + idx;
                int s, d;
                if (e < N_EDGES) { s = ei[e]; d = ei[N_EDGES + e]; }
                else             { s = d = (int)(e - N_EDGES); }
                myb[i] = d >> BSH;
                mye[i] = ((unsigned)(d & 127) << 17) | (unsigned)s;
                atomicAdd(&cnt[myb[i]], 1);
            }
        }
        __syncthreads();
        for (int ofs = 1; ofs < 512; ofs <<= 1) {
            int v0 = (t >= ofs) ? cnt[t - ofs] : 0;
            int v1 = cnt[t + 256 - ofs];
            __syncthreads();
            cnt[t] += v0; cnt[t + 256] += v1;
            __syncthreads();
        }
        for (int b = t; b < NBUCK; b += 256) {
            base[b] = (b == 0) ? 0 : cnt[b - 1];
            int c = cnt[b] - base[b];
            gpos[b] = (c > 0) ? atomicAdd(&gcur[b], c) : 0;
        }
        __syncthreads();
        #pragma unroll
        for (int i = 0; i < per; ++i) {
            if (myb[i] >= 0) {
                int slot = base[myb[i]] + atomicAdd(&cnt2[myb[i]], 1);
                stage[slot] = mye[i];
                bof[slot] = (unsigned short)myb[i];
            }
        }
        __syncthreads();
        for (int i = t; i < nE; i += 256) {
            int b = bof[i];
            int pos = gpos[b] + (i - base[b]);
            if (pos < BCAP)
                bbuf[(size_t)b * BCAP + pos] = stage[i];
        }
    } else {
        // ---------------- GEMM1 path (MFMA, fused attention dots) ----------
        unsigned short (*W1T)[136] = (unsigned short(*)[136])smem;  // 17.4 KB
        float* psA = (float*)(smem + 17408);   // 4*16 f32
        float* psD = (float*)(smem + 17664);   // 4*16 f32

        const int wave = t >> 6, lane = t & 63;
        const int quad = lane >> 4, lm = lane & 15;
        for (int i = t; i < 128 * 64; i += 256)
            W1T[i & 63][i >> 6] = f2bf(W1[i]);   // W1T[c][k] = W1[k][c]
        __syncthreads();

        const int c = wave * 16 + lm;            // this lane's output column
        bf16x8 bfr[4];
        #pragma unroll
        for (int s = 0; s < 4; ++s)
            bfr[s] = *(const bf16x8*)&W1T[c][s * 32 + quad * 8];
        const float asc = att_s[c], adc = att_d[c];

        const int r0 = (blockIdx.x - NCHUNKS) * 16;
        f32x4 acc = {0.f, 0.f, 0.f, 0.f};
        #pragma unroll
        for (int s = 0; s < 4; ++s) {
            const float* xp = &x[(size_t)(r0 + lm) * 128 + s * 32 + quad * 8];
            float4 xa = *(const float4*)xp;
            float4 xb = *(const float4*)(xp + 4);
            bf16x8 afr;
            afr[0] = (short)f2bf(xa.x); afr[1] = (short)f2bf(xa.y);
            afr[2] = (short)f2bf(xa.z); afr[3] = (short)f2bf(xa.w);
            afr[4] = (short)f2bf(xb.x); afr[5] = (short)f2bf(xb.y);
            afr[6] = (short)f2bf(xb.z); afr[7] = (short)f2bf(xb.w);
            acc = __builtin_amdgcn_mfma_f32_16x16x32_bf16(afr, bfr[s], acc, 0, 0, 0);
        }
        float psv[4], pdv[4];
        #pragma unroll
        for (int r = 0; r < 4; ++r) {
            float v = acc[r];
            xl1[(size_t)(r0 + quad * 4 + r) * 64 + c] = f2bf(v);
            psv[r] = v * asc;
            pdv[r] = v * adc;
        }
        #pragma unroll
        for (int ofs = 1; ofs <= 8; ofs <<= 1) {
            #pragma unroll
            for (int r = 0; r < 4; ++r) {
                psv[r] += __shfl_xor(psv[r], ofs, 64);
                pdv[r] += __shfl_xor(pdv[r], ofs, 64);
            }
        }
        if (lm == 0) {
            #pragma unroll
            for (int r = 0; r < 4; ++r) {
                psA[wave * 16 + quad * 4 + r] = psv[r];
                psD[wave * 16 + quad * 4 + r] = pdv[r];
            }
        }
        __syncthreads();
        if (t < 32) {
            const int row = t & 15, h = t >> 4;
            a_s[(size_t)(r0 + row) * 2 + h] = psA[(2 * h) * 16 + row] + psA[(2 * h + 1) * 16 + row];
            a_d[(size_t)(r0 + row) * 2 + h] = psD[(2 * h) * 16 + row] + psD[(2 * h + 1) * 16 + row];
        }
    }
}

// -------- pass 2: per-bucket counting sort, emits beg/end (light version) ---
__global__ __launch_bounds__(256) void k_bsort(
    const int* __restrict__ gcur, unsigned* __restrict__ bbuf,
    int* __restrict__ beg, int* __restrict__ end)
{
    __shared__ unsigned est[BCAP];   // 20 KB
    __shared__ unsigned sst[BCAP];   // 20 KB
    __shared__ int c[128], lbase[128], c2[128];
    const int b = blockIdx.x, t = threadIdx.x;
    const int n = min(gcur[b], BCAP);
    unsigned* reg = bbuf + (size_t)b * BCAP;
    for (int i = t; i < n; i += 256) est[i] = reg[i];
    if (t < 128) { c[t] = 0; c2[t] = 0; }
    __syncthreads();
    for (int i = t; i < n; i += 256) atomicAdd(&c[est[i] >> 17], 1);
    __syncthreads();
    for (int ofs = 1; ofs < 128; ofs <<= 1) {
        int v = (t < 128 && t >= ofs) ? c[t - ofs] : 0;
        __syncthreads();
        if (t < 128) c[t] += v;
        __syncthreads();
    }
    if (t < 128) {
        lbase[t] = (t == 0) ? 0 : c[t - 1];
        int dst = (b << BSH) + t;
        if (dst < N_NODES) {
            beg[dst] = b * BCAP + lbase[t];
            end[dst] = b * BCAP + c[t];
        }
    }
    __syncthreads();
    for (int i = t; i < n; i += 256) {
        unsigned v = est[i];
        int dl = (int)(v >> 17);
        int pos = lbase[dl] + atomicAdd(&c2[dl], 1);
        sst[pos] = v & 0x1FFFFu;             // strip dl bits -> pure src index
    }
    __syncthreads();
    for (int i = t; i < n; i += 256) reg[i] = sst[i];
}

// ------- layer-1 attention: 128-thr blocks (2 dsts), inline weights ---------
#define FMA8(vv, ww) do { \
    acc[0] = fmaf(bf_lo(vv.x), ww, acc[0]); acc[1] = fmaf(bf_hi(vv.x), ww, acc[1]); \
    acc[2] = fmaf(bf_lo(vv.y), ww, acc[2]); acc[3] = fmaf(bf_hi(vv.y), ww, acc[3]); \
    acc[4] = fmaf(bf_lo(vv.z), ww, acc[4]); acc[5] = fmaf(bf_hi(vv.z), ww, acc[5]); \
    acc[6] = fmaf(bf_lo(vv.w), ww, acc[6]); acc[7] = fmaf(bf_hi(vv.w), ww, acc[7]); \
} while (0)

__global__ __launch_bounds__(128) void k_attn1(
    const int* __restrict__ beg_a, const int* __restrict__ end_a,
    const unsigned* __restrict__ csr,
    const float* __restrict__ a_s, const float* __restrict__ a_d,
    const unsigned short* __restrict__ xl, const float* __restrict__ b1,
    unsigned short* __restrict__ hout)    // [N][64] bf16: elu(aggregate + b1)
{
    const int wave = threadIdx.x >> 6, lane = threadIdx.x & 63;
    const int dst = blockIdx.x * 2 + wave;
    const int beg = beg_a[dst], end = end_a[dst];
    const int li = lane & 7, sub = lane >> 3, hh = li >> 2;
    const float adh = a_d[(size_t)dst * 2 + hh];   // wave-uniform per head

    float acc[8];
    #pragma unroll
    for (int i = 0; i < 8; ++i) acc[i] = 0.f;
    float wsum = 0.f;

    int k = beg;
    // main loop: all 32 slots valid, no masks, no clamps
    for (; k + 32 <= end; k += 32) {
        const int i0 = k + sub;
        const int s0 = (int)csr[i0];
        const int s1 = (int)csr[i0 + 8];
        const int s2 = (int)csr[i0 + 16];
        const int s3 = (int)csr[i0 + 24];
        const float w0 = lrelu_exp(a_s[(size_t)s0 * 2 + hh] + adh);
        const float w1 = lrelu_exp(a_s[(size_t)s1 * 2 + hh] + adh);
        const float w2 = lrelu_exp(a_s[(size_t)s2 * 2 + hh] + adh);
        const float w3 = lrelu_exp(a_s[(size_t)s3 * 2 + hh] + adh);
        uint4 v0 = *(const uint4*)&xl[(size_t)s0 * 64 + li * 8];
        uint4 v1 = *(const uint4*)&xl[(size_t)s1 * 64 + li * 8];
        uint4 v2 = *(const uint4*)&xl[(size_t)s2 * 64 + li * 8];
        uint4 v3 = *(const uint4*)&xl[(size_t)s3 * 64 + li * 8];
        wsum += w0 + w1 + w2 + w3;
        FMA8(v0, w0);
        FMA8(v1, w1);
        FMA8(v2, w2);
        FMA8(v3, w3);
    }
    // tail: 8 edges per iteration, masked
    const int last = end - 1;              // >= beg (self-loop guarantees >=1 edge)
    for (; k < end; k += 8) {
        const int i0 = k + sub;
        const int c0 = min(i0, last);
        const int s0 = (int)csr[c0];
        float w0 = lrelu_exp(a_s[(size_t)s0 * 2 + hh] + adh);
        if (i0 >= end) w0 = 0.f;
        uint4 v0 = *(const uint4*)&xl[(size_t)s0 * 64 + li * 8];
        wsum += w0;
        FMA8(v0, w0);
    }
    #pragma unroll
    for (int ofs = 8; ofs <= 32; ofs <<= 1) {
        wsum += __shfl_xor(wsum, ofs, 64);
        #pragma unroll
        for (int i = 0; i < 8; ++i) acc[i] += __shfl_xor(acc[i], ofs, 64);
    }
    if (sub == 0) {
        const float4 b1a = *(const float4*)&b1[li * 8];
        const float4 b1b = *(const float4*)&b1[li * 8 + 4];
        const float inv = 1.f / wsum;
        float h0 = elu_f(acc[0] * inv + b1a.x);
        float h1 = elu_f(acc[1] * inv + b1a.y);
        float h2 = elu_f(acc[2] * inv + b1a.z);
        float h3 = elu_f(acc[3] * inv + b1a.w);
        float h4 = elu_f(acc[4] * inv + b1b.x);
        float h5 = elu_f(acc[5] * inv + b1b.y);
        float h6 = elu_f(acc[6] * inv + b1b.z);
        float h7 = elu_f(acc[7] * inv + b1b.w);
        uint4 p;
        p.x = (unsigned)f2bf(h0) | ((unsigned)f2bf(h1) << 16);
        p.y = (unsigned)f2bf(h2) | ((unsigned)f2bf(h3) << 16);
        p.z = (unsigned)f2bf(h4) | ((unsigned)f2bf(h5) << 16);
        p.w = (unsigned)f2bf(h6) | ((unsigned)f2bf(h7) << 16);
        *(uint4*)&hout[(size_t)dst * 64 + li * 8] = p;
    }
}

// ---------------- GEMM2 via MFMA: xl2(fp8) = h @ W2, fused attention dots ----
__global__ __launch_bounds__(256) void k_gemm2m(
    const unsigned short* __restrict__ h, const float* __restrict__ W2,
    const float* __restrict__ att_s, const float* __restrict__ att_d,
    unsigned char* __restrict__ xl2, float* __restrict__ a_s, float* __restrict__ a_d)
{
    __shared__ unsigned short W2T[128][72];  // W2^T bf16, pad 72 (18.4 KB)
    __shared__ float psA[4][16], psD[4][16];
    const int t = threadIdx.x, wave = t >> 6, lane = t & 63;
    const int quad = lane >> 4, lm = lane & 15;
    for (int i = t; i < 64 * 128; i += 256)
        W2T[i & 127][i >> 7] = f2bf(W2[i]);  // W2T[c][k] = W2[k][c]
    __syncthreads();

    const int c0 = wave * 32 + lm;
    const int c1 = c0 + 16;
    bf16x8 bfr0[2], bfr1[2];
    #pragma unroll
    for (int s = 0; s < 2; ++s) {
        bfr0[s] = *(const bf16x8*)&W2T[c0][s * 32 + quad * 8];
        bfr1[s] = *(const bf16x8*)&W2T[c1][s * 32 + quad * 8];
    }
    const float as0 = att_s[c0], as1 = att_s[c1];
    const float ad0 = att_d[c0], ad1 = att_d[c1];

    const int r0 = blockIdx.x * 16;
    f32x4 acc0 = {0.f, 0.f, 0.f, 0.f}, acc1 = {0.f, 0.f, 0.f, 0.f};
    #pragma unroll
    for (int s = 0; s < 2; ++s) {
        bf16x8 afr = *(const bf16x8*)&h[(size_t)(r0 + lm) * 64 + s * 32 + quad * 8];
        acc0 = __builtin_amdgcn_mfma_f32_16x16x32_bf16(afr, bfr0[s], acc0, 0, 0, 0);
        acc1 = __builtin_amdgcn_mfma_f32_16x16x32_bf16(afr, bfr1[s], acc1, 0, 0, 0);
    }
    float psv[4], pdv[4];
    #pragma unroll
    for (int r = 0; r < 4; ++r) {
        float v0 = acc0[r], v1 = acc1[r];
        const size_t row = (size_t)(r0 + quad * 4 + r) * 128;
        xl2[row + c0] = f2fp8(v0);          // fp8 e4m3 gather table
        xl2[row + c1] = f2fp8(v1);
        psv[r] = v0 * as0 + v1 * as1;       // logits from fp32 (pre-quant)
        pdv[r] = v0 * ad0 + v1 * ad1;
    }
    #pragma unroll
    for (int ofs = 1; ofs <= 8; ofs <<= 1) {
        #pragma unroll
        for (int r = 0; r < 4; ++r) {
            psv[r] += __shfl_xor(psv[r], ofs, 64);
            pdv[r] += __shfl_xor(pdv[r], ofs, 64);
        }
    }
    if (lm == 0) {
        #pragma unroll
        for (int r = 0; r < 4; ++r) {
            psA[wave][quad * 4 + r] = psv[r];
            psD[wave][quad * 4 + r] = pdv[r];
        }
    }
    __syncthreads();
    if (t < 16) {
        a_s[r0 + t] = psA[0][t] + psA[1][t] + psA[2][t] + psA[3][t];
        a_d[r0 + t] = psD[0][t] + psD[1][t] + psD[2][t] + psD[3][t];
    }
}

// ------- layer-2 attention: 128-thr blocks (2 dsts), fp8 gather, bf16 out ---
#define CFMA16(vv, ww) do { \
    f32x2 p_; \
    p_ = __builtin_amdgcn_cvt_pk_f32_fp8(vv.x, false); acc[0]  = fmaf(p_.x, ww, acc[0]);  acc[1]  = fmaf(p_.y, ww, acc[1]);  \
    p_ = __builtin_amdgcn_cvt_pk_f32_fp8(vv.x, true);  acc[2]  = fmaf(p_.x, ww, acc[2]);  acc[3]  = fmaf(p_.y, ww, acc[3]);  \
    p_ = __builtin_amdgcn_cvt_pk_f32_fp8(vv.y, false); acc[4]  = fmaf(p_.x, ww, acc[4]);  acc[5]  = fmaf(p_.y, ww, acc[5]);  \
    p_ = __builtin_amdgcn_cvt_pk_f32_fp8(vv.y, true);  acc[6]  = fmaf(p_.x, ww, acc[6]);  acc[7]  = fmaf(p_.y, ww, acc[7]);  \
    p_ = __builtin_amdgcn_cvt_pk_f32_fp8(vv.z, false); acc[8]  = fmaf(p_.x, ww, acc[8]);  acc[9]  = fmaf(p_.y, ww, acc[9]);  \
    p_ = __builtin_amdgcn_cvt_pk_f32_fp8(vv.z, true);  acc[10] = fmaf(p_.x, ww, acc[10]); acc[11] = fmaf(p_.y, ww, acc[11]); \
    p_ = __builtin_amdgcn_cvt_pk_f32_fp8(vv.w, false); acc[12] = fmaf(p_.x, ww, acc[12]); acc[13] = fmaf(p_.y, ww, acc[13]); \
    p_ = __builtin_amdgcn_cvt_pk_f32_fp8(vv.w, true);  acc[14] = fmaf(p_.x, ww, acc[14]); acc[15] = fmaf(p_.y, ww, acc[15]); \
} while (0)

__global__ __launch_bounds__(128) void k_attn2(
    const int* __restrict__ beg_a, const int* __restrict__ end_a,
    const unsigned* __restrict__ csr,
    const float* __restrict__ a_s, const float* __restrict__ a_d,
    const unsigned char* __restrict__ xl, unsigned short* __restrict__ out)
{
    const int wave = threadIdx.x >> 6, lane = threadIdx.x & 63;
    const int dst = blockIdx.x * 2 + wave;
    const int beg = beg_a[dst], end = end_a[dst];
    const int li = lane & 7, sub = lane >> 3;   // ch group li*16..+15; edge slot
    const float ad0 = a_d[dst];                 // wave-uniform

    float acc[16];
    #pragma unroll
    for (int i = 0; i < 16; ++i) acc[i] = 0.f;
    float wsum = 0.f;

    int k = beg;
    // main loop: all 32 slots valid, no masks, no clamps
    for (; k + 32 <= end; k += 32) {
        const int i0 = k + sub;
        const int s0 = (int)csr[i0];
        const int s1 = (int)csr[i0 + 8];
        const int s2 = (int)csr[i0 + 16];
        const int s3 = (int)csr[i0 + 24];
        const float w0 = lrelu_exp(a_s[s0] + ad0);
        const float w1 = lrelu_exp(a_s[s1] + ad0);
        const float w2 = lrelu_exp(a_s[s2] + ad0);
        const float w3 = lrelu_exp(a_s[s3] + ad0);
        uint4 v0 = *(const uint4*)&xl[(size_t)s0 * 128 + li * 16];
        uint4 v1 = *(const uint4*)&xl[(size_t)s1 * 128 + li * 16];
        uint4 v2 = *(const uint4*)&xl[(size_t)s2 * 128 + li * 16];
        uint4 v3 = *(const uint4*)&xl[(size_t)s3 * 128 + li * 16];
        wsum += w0 + w1 + w2 + w3;
        CFMA16(v0, w0);
        CFMA16(v1, w1);
        CFMA16(v2, w2);
        CFMA16(v3, w3);
    }
    // tail: 8 edges per iteration, masked
    const int last = end - 1;
    for (; k < end; k += 8) {
        const int i0 = k + sub;
        const int c0 = min(i0, last);
        const int s0 = (int)csr[c0];
        float w0 = lrelu_exp(a_s[s0] + ad0);
        if (i0 >= end) w0 = 0.f;
        uint4 v0 = *(const uint4*)&xl[(size_t)s0 * 128 + li * 16];
        wsum += w0;
        CFMA16(v0, w0);
    }
    #pragma unroll
    for (int ofs = 8; ofs <= 32; ofs <<= 1) {
        wsum += __shfl_xor(wsum, ofs, 64);
        #pragma unroll
        for (int i = 0; i < 16; ++i) acc[i] += __shfl_xor(acc[i], ofs, 64);
    }
    if (sub == 0) {
        const float inv = 1.f / wsum;
        unsigned short* op = &out[(size_t)dst * 128 + li * 16];
        uint4 pa, pb;
        pa.x = (unsigned)f2bf(acc[0]  * inv) | ((unsigned)f2bf(acc[1]  * inv) << 16);
        pa.y = (unsigned)f2bf(acc[2]  * inv) | ((unsigned)f2bf(acc[3]  * inv) << 16);
        pa.z = (unsigned)f2bf(acc[4]  * inv) | ((unsigned)f2bf(acc[5]  * inv) << 16);
        pa.w = (unsigned)f2bf(acc[6]  * inv) | ((unsigned)f2bf(acc[7]  * inv) << 16);
        pb.x = (unsigned)f2bf(acc[8]  * inv) | ((unsigned)f2bf(acc[9]  * inv) << 16);
        pb.y = (unsigned)f2bf(acc[10] * inv) | ((unsigned)f2bf(acc[11] * inv) << 16);
        pb.z = (unsigned)f2bf(acc[12] * inv) | ((unsigned)f2bf(acc[13] * inv) << 16);
        pb.w = (unsigned)f2bf(acc[14] * inv) | ((unsigned)f2bf(acc[15] * inv) << 16);
        *(uint4*)op       = pa;
        *(uint4*)(op + 8) = pb;
    }
}

// ---------------- pooling: 32 nodes/block, 2 node-lanes x 128 ch (bf16 in) ---
__global__ __launch_bounds__(256) void k_pool(
    const unsigned short* __restrict__ out2, const float* __restrict__ b2,
    const int* __restrict__ batch, float* __restrict__ sums, float* __restrict__ cnts)
{
    const int c    = threadIdx.x & 127;
    const int half = threadIdx.x >> 7;
    const int n0   = blockIdx.x * PN;
    const int nb   = n0 + half;
    if (nb >= N_NODES) return;
    const float bc = b2[c];
    float acc = 0.f;
    int cur = batch[nb], cnt = 0;
    for (int i = half; i < PN; i += 2) {
        int n = n0 + i;
        if (n >= N_NODES) break;
        int g = batch[n];
        if (g != cur) {
            atomicAdd(&sums[cur * OUT_CH + c], acc);
            if (c == 0) atomicAdd(&cnts[cur], (float)cnt);
            acc = 0.f; cnt = 0; cur = g;
        }
        float v = __uint_as_float((unsigned)out2[(size_t)n * OUT_CH + c] << 16);
        acc += elu_f(v + bc);
        cnt++;
    }
    if (cnt > 0) {
        atomicAdd(&sums[cur * OUT_CH + c], acc);
        if (c == 0) atomicAdd(&cnts[cur], (float)cnt);
    }
}

__global__ __launch_bounds__(256) void k_final(
    const float* __restrict__ sums, const float* __restrict__ cnts,
    float* __restrict__ out)
{
    int i = blockIdx.x * 256 + threadIdx.x;
    if (i >= N_GRAPHS * OUT_CH) return;
    out[i] = sums[i] / fmaxf(cnts[i >> 7], 1.f);
}

extern "C" void kernel_launch(void* const* d_in, const int* in_sizes, int n_in,
                              void* d_out, int out_size, void* d_ws, size_t ws_size,
                              hipStream_t stream)
{
    const float* x    = (const float*)d_in[0];
    const int*   ei   = (const int*)d_in[1];
    const int*   batch= (const int*)d_in[2];
    const float* W1   = (const float*)d_in[3];
    const float* as1  = (const float*)d_in[4];
    const float* ad1  = (const float*)d_in[5];
    const float* b1   = (const float*)d_in[6];
    const float* W2   = (const float*)d_in[7];
    const float* as2  = (const float*)d_in[8];
    const float* ad2  = (const float*)d_in[9];
    const float* b2   = (const float*)d_in[10];

    float* ws = (float*)d_ws;
    size_t o = 0;
    unsigned short* xl1b = (unsigned short*)(ws + o); o += (size_t)N_NODES * C1 / 2;
    unsigned short* hbuf = (unsigned short*)(ws + o); o += (size_t)N_NODES * C1 / 2;
    unsigned char*  xl2q = (unsigned char*)(ws + o);  o += (size_t)N_NODES * OUT_CH / 4;
    float*    a_s1 = ws + o; o += (size_t)N_NODES * 2;
    float*    a_d1 = ws + o; o += (size_t)N_NODES * 2;
    float*    a_s2 = ws + o; o += (size_t)N_NODES;
    float*    a_d2 = ws + o; o += (size_t)N_NODES;
    unsigned short* out2b = (unsigned short*)(ws + o); o += (size_t)N_NODES * OUT_CH / 2;
    unsigned* bbuf = (unsigned*)(ws + o); o += (size_t)NBUCK * BCAP;
    int*      beg  = (int*)(ws + o); o += (size_t)N_NODES;
    int*      end  = (int*)(ws + o); o += (size_t)N_NODES;
    size_t zero_start = o;
    int*      gcur = (int*)(ws + o); o += (size_t)NBUCK;
    float*    sums = ws + o;         o += (size_t)N_GRAPHS * OUT_CH;
    float*    cnts = ws + o;         o += (size_t)N_GRAPHS;
    size_t zero_bytes = (o - zero_start) * sizeof(float);
    hipMemsetAsync(ws + zero_start, 0, zero_bytes, stream);

    k_g1bin<<<NCHUNKS + N_NODES / 16, 256, 0, stream>>>(
        x, W1, as1, ad1, xl1b, a_s1, a_d1, ei, gcur, bbuf);
    k_bsort<<<NBUCK, 256, 0, stream>>>(gcur, bbuf, beg, end);
    k_attn1<<<N_NODES / 2, 128, 0, stream>>>(beg, end, bbuf, a_s1, a_d1, xl1b, b1, hbuf);
    k_gemm2m<<<(N_NODES + 15) / 16, 256, 0, stream>>>(hbuf, W2, as2, ad2, xl2q, a_s2, a_d2);
    k_attn2<<<N_NODES / 2, 128, 0, stream>>>(beg, end, bbuf, a_s2, a_d2, xl2q, out2b);
    k_pool<<<(N_NODES + PN - 1) / PN, 256, 0, stream>>>(out2b, b2, batch, sums, cnts);
    k_final<<<(N_GRAPHS * OUT_CH + 255) / 256, 256, 0, stream>>>(sums, cnts, (float*)d_out);
}

// Round 11
// 245.335 us; speedup vs baseline: 1.1634x; 1.0200x over previous
//
#include <hip/hip_runtime.h>

#define N_NODES 50000
#define N_EDGES 1600000
#define E_TOT   (N_EDGES + N_NODES)   // 1,650,000 incl. self-loops
#define IN_CH   128
#define C1      64                    // heads(2) * hid(32)
#define OUT_CH  128
#define N_GRAPHS 64
#define NEG_SLOPE 0.2f

#define BSH   7                        // 128 dsts per bucket
#define NBUCK ((N_NODES + 127) / 128)  // 391
#define BCAP  5120                     // per-bucket region cap (mean 4220, ~14 sigma)
#define CHUNK 4096                     // edges per bin block (halved: LDS 30.6 KB -> 5 blk/CU)
#define NCHUNKS ((E_TOT + CHUNK - 1) / CHUNK)   // 403
#define PN    32                       // nodes per k_pool block

typedef __attribute__((ext_vector_type(8))) short bf16x8;
typedef __attribute__((ext_vector_type(4))) float f32x4;
typedef __attribute__((ext_vector_type(2))) float f32x2;

__device__ __forceinline__ float elu_f(float v) {
    return v > 0.f ? v : (__expf(v) - 1.f);
}
__device__ __forceinline__ unsigned short f2bf(float f) {   // RNE
    unsigned u = __float_as_uint(f);
    return (unsigned short)((u + 0x7FFFu + ((u >> 16) & 1u)) >> 16);
}
__device__ __forceinline__ float bf_lo(unsigned u) { return __uint_as_float(u << 16); }
__device__ __forceinline__ float bf_hi(unsigned u) { return __uint_as_float(u & 0xFFFF0000u); }
__device__ __forceinline__ unsigned char f2fp8(float v) {   // OCP e4m3 via HW cvt
    return (unsigned char)(__builtin_amdgcn_cvt_pk_fp8_f32(v, v, 0, false) & 0xFF);
}
__device__ __forceinline__ float lrelu_exp(float e) {
    e = e > 0.f ? e : NEG_SLOPE * e;
    return __expf(e);
}

// ---- fused: blocks [0,NCHUNKS) = edge binning; blocks [NCHUNKS,..) = GEMM1 --
// Independent bodies co-execute in one dispatch (serial sum -> max). LDS is a
// 30.6 KB union (CHUNK=4096) so both paths get ~5 blocks/CU.
__global__ __launch_bounds__(256) void k_g1bin(
    const float* __restrict__ x, const float* __restrict__ W1,
    const float* __restrict__ att_s, const float* __restrict__ att_d,
    unsigned short* __restrict__ xl1, float* __restrict__ a_s, float* __restrict__ a_d,
    const int* __restrict__ ei, int* __restrict__ gcur, unsigned* __restrict__ bbuf)
{
    __shared__ __align__(16) char smem[31360];   // bin: 30.6 KB; gemm1: 17.9 KB
    const int t = threadIdx.x;

    if (blockIdx.x < NCHUNKS) {
        // ---------------- bin path (LDS-staged binning by dst>>7) ----------
        int* cnt  = (int*)smem;                       // 512 ints
        int* base = (int*)(smem + 2048);              // NBUCK
        int* cnt2 = (int*)(smem + 3612);              // NBUCK
        int* gpos = (int*)(smem + 5176);              // NBUCK  (ends 6740)
        unsigned* stage = (unsigned*)(smem + 6740);   // CHUNK (16 KB, ends 23124)
        unsigned short* bof = (unsigned short*)(smem + 23124);  // CHUNK (8 KB)

        const long long e0 = (long long)blockIdx.x * CHUNK;
        const int nE = (int)min((long long)CHUNK, (long long)E_TOT - e0);

        cnt[t] = 0; cnt[t + 256] = 0;
        for (int b = t; b < NBUCK; b += 256) cnt2[b] = 0;
        __syncthreads();

        const int per = CHUNK / 256;           // 16
        int myb[per]; unsigned mye[per];
        #pragma unroll
        for (int i = 0; i < per; ++i) {
            int idx = t + 256 * i;
            myb[i] = -1;
            if (idx < nE) {
                long long e = e0 + idx;
                int s, d;
                if (e < N_EDGES) { s = ei[e]; d = ei[N_EDGES + e]; }
                else             { s = d = (int)(e - N_EDGES); }
                myb[i] = d >> BSH;
                mye[i] = ((unsigned)(d & 127) << 17) | (unsigned)s;
                atomicAdd(&cnt[myb[i]], 1);
            }
        }
        __syncthreads();
        for (int ofs = 1; ofs < 512; ofs <<= 1) {
            int v0 = (t >= ofs) ? cnt[t - ofs] : 0;
            int v1 = cnt[t + 256 - ofs];
            __syncthreads();
            cnt[t] += v0; cnt[t + 256] += v1;
            __syncthreads();
        }
        for (int b = t; b < NBUCK; b += 256) {
            base[b] = (b == 0) ? 0 : cnt[b - 1];
            int c = cnt[b] - base[b];
            gpos[b] = (c > 0) ? atomicAdd(&gcur[b], c) : 0;
        }
        __syncthreads();
        #pragma unroll
        for (int i = 0; i < per; ++i) {
            if (myb[i] >= 0) {
                int slot = base[myb[i]] + atomicAdd(&cnt2[myb[i]], 1);
                stage[slot] = mye[i];
                bof[slot] = (unsigned short)myb[i];
            }
        }
        __syncthreads();
        for (int i = t; i < nE; i += 256) {
            int b = bof[i];
            int pos = gpos[b] + (i - base[b]);
            if (pos < BCAP)
                bbuf[(size_t)b * BCAP + pos] = stage[i];
        }
    } else {
        // ---------------- GEMM1 path (MFMA, fused attention dots) ----------
        unsigned short (*W1T)[136] = (unsigned short(*)[136])smem;  // 17.4 KB
        float* psA = (float*)(smem + 17408);   // 4*16 f32
        float* psD = (float*)(smem + 17664);   // 4*16 f32

        const int wave = t >> 6, lane = t & 63;
        const int quad = lane >> 4, lm = lane & 15;
        for (int i = t; i < 128 * 64; i += 256)
            W1T[i & 63][i >> 6] = f2bf(W1[i]);   // W1T[c][k] = W1[k][c]
        __syncthreads();

        const int c = wave * 16 + lm;            // this lane's output column
        bf16x8 bfr[4];
        #pragma unroll
        for (int s = 0; s < 4; ++s)
            bfr[s] = *(const bf16x8*)&W1T[c][s * 32 + quad * 8];
        const float asc = att_s[c], adc = att_d[c];

        const int r0 = (blockIdx.x - NCHUNKS) * 16;
        f32x4 acc = {0.f, 0.f, 0.f, 0.f};
        #pragma unroll
        for (int s = 0; s < 4; ++s) {
            const float* xp = &x[(size_t)(r0 + lm) * 128 + s * 32 + quad * 8];
            float4 xa = *(const float4*)xp;
            float4 xb = *(const float4*)(xp + 4);
            bf16x8 afr;
            afr[0] = (short)f2bf(xa.x); afr[1] = (short)f2bf(xa.y);
            afr[2] = (short)f2bf(xa.z); afr[3] = (short)f2bf(xa.w);
            afr[4] = (short)f2bf(xb.x); afr[5] = (short)f2bf(xb.y);
            afr[6] = (short)f2bf(xb.z); afr[7] = (short)f2bf(xb.w);
            acc = __builtin_amdgcn_mfma_f32_16x16x32_bf16(afr, bfr[s], acc, 0, 0, 0);
        }
        float psv[4], pdv[4];
        #pragma unroll
        for (int r = 0; r < 4; ++r) {
            float v = acc[r];
            xl1[(size_t)(r0 + quad * 4 + r) * 64 + c] = f2bf(v);
            psv[r] = v * asc;
            pdv[r] = v * adc;
        }
        #pragma unroll
        for (int ofs = 1; ofs <= 8; ofs <<= 1) {
            #pragma unroll
            for (int r = 0; r < 4; ++r) {
                psv[r] += __shfl_xor(psv[r], ofs, 64);
                pdv[r] += __shfl_xor(pdv[r], ofs, 64);
            }
        }
        if (lm == 0) {
            #pragma unroll
            for (int r = 0; r < 4; ++r) {
                psA[wave * 16 + quad * 4 + r] = psv[r];
                psD[wave * 16 + quad * 4 + r] = pdv[r];
            }
        }
        __syncthreads();
        if (t < 32) {
            const int row = t & 15, h = t >> 4;
            a_s[(size_t)(r0 + row) * 2 + h] = psA[(2 * h) * 16 + row] + psA[(2 * h + 1) * 16 + row];
            a_d[(size_t)(r0 + row) * 2 + h] = psD[(2 * h) * 16 + row] + psD[(2 * h + 1) * 16 + row];
        }
    }
}

// -------- pass 2: per-bucket counting sort, emits beg/end (light version) ---
__global__ __launch_bounds__(256) void k_bsort(
    const int* __restrict__ gcur, unsigned* __restrict__ bbuf,
    int* __restrict__ beg, int* __restrict__ end)
{
    __shared__ unsigned est[BCAP];   // 20 KB
    __shared__ unsigned sst[BCAP];   // 20 KB
    __shared__ int c[128], lbase[128], c2[128];
    const int b = blockIdx.x, t = threadIdx.x;
    const int n = min(gcur[b], BCAP);
    unsigned* reg = bbuf + (size_t)b * BCAP;
    for (int i = t; i < n; i += 256) est[i] = reg[i];
    if (t < 128) { c[t] = 0; c2[t] = 0; }
    __syncthreads();
    for (int i = t; i < n; i += 256) atomicAdd(&c[est[i] >> 17], 1);
    __syncthreads();
    for (int ofs = 1; ofs < 128; ofs <<= 1) {
        int v = (t < 128 && t >= ofs) ? c[t - ofs] : 0;
        __syncthreads();
        if (t < 128) c[t] += v;
        __syncthreads();
    }
    if (t < 128) {
        lbase[t] = (t == 0) ? 0 : c[t - 1];
        int dst = (b << BSH) + t;
        if (dst < N_NODES) {
            beg[dst] = b * BCAP + lbase[t];
            end[dst] = b * BCAP + c[t];
        }
    }
    __syncthreads();
    for (int i = t; i < n; i += 256) {
        unsigned v = est[i];
        int dl = (int)(v >> 17);
        int pos = lbase[dl] + atomicAdd(&c2[dl], 1);
        sst[pos] = v & 0x1FFFFu;             // strip dl bits -> pure src index
    }
    __syncthreads();
    for (int i = t; i < n; i += 256) reg[i] = sst[i];
}

// ------- layer-1 attention: 128-thr blocks (2 dsts), inline weights ---------
#define FMA8(vv, ww) do { \
    acc[0] = fmaf(bf_lo(vv.x), ww, acc[0]); acc[1] = fmaf(bf_hi(vv.x), ww, acc[1]); \
    acc[2] = fmaf(bf_lo(vv.y), ww, acc[2]); acc[3] = fmaf(bf_hi(vv.y), ww, acc[3]); \
    acc[4] = fmaf(bf_lo(vv.z), ww, acc[4]); acc[5] = fmaf(bf_hi(vv.z), ww, acc[5]); \
    acc[6] = fmaf(bf_lo(vv.w), ww, acc[6]); acc[7] = fmaf(bf_hi(vv.w), ww, acc[7]); \
} while (0)

__global__ __launch_bounds__(128) void k_attn1(
    const int* __restrict__ beg_a, const int* __restrict__ end_a,
    const unsigned* __restrict__ csr,
    const float* __restrict__ a_s, const float* __restrict__ a_d,
    const unsigned short* __restrict__ xl, const float* __restrict__ b1,
    unsigned short* __restrict__ hout)    // [N][64] bf16: elu(aggregate + b1)
{
    const int wave = threadIdx.x >> 6, lane = threadIdx.x & 63;
    const int dst = blockIdx.x * 2 + wave;
    const int beg = beg_a[dst], end = end_a[dst];
    const int li = lane & 7, sub = lane >> 3, hh = li >> 2;
    const float adh = a_d[(size_t)dst * 2 + hh];   // wave-uniform per head

    float acc[8];
    #pragma unroll
    for (int i = 0; i < 8; ++i) acc[i] = 0.f;
    float wsum = 0.f;

    int k = beg;
    // main loop: all 32 slots valid, no masks, no clamps
    for (; k + 32 <= end; k += 32) {
        const int i0 = k + sub;
        const int s0 = (int)csr[i0];
        const int s1 = (int)csr[i0 + 8];
        const int s2 = (int)csr[i0 + 16];
        const int s3 = (int)csr[i0 + 24];
        const float w0 = lrelu_exp(a_s[(size_t)s0 * 2 + hh] + adh);
        const float w1 = lrelu_exp(a_s[(size_t)s1 * 2 + hh] + adh);
        const float w2 = lrelu_exp(a_s[(size_t)s2 * 2 + hh] + adh);
        const float w3 = lrelu_exp(a_s[(size_t)s3 * 2 + hh] + adh);
        uint4 v0 = *(const uint4*)&xl[(size_t)s0 * 64 + li * 8];
        uint4 v1 = *(const uint4*)&xl[(size_t)s1 * 64 + li * 8];
        uint4 v2 = *(const uint4*)&xl[(size_t)s2 * 64 + li * 8];
        uint4 v3 = *(const uint4*)&xl[(size_t)s3 * 64 + li * 8];
        wsum += w0 + w1 + w2 + w3;
        FMA8(v0, w0);
        FMA8(v1, w1);
        FMA8(v2, w2);
        FMA8(v3, w3);
    }
    // tail: 8 edges per iteration, masked
    const int last = end - 1;              // >= beg (self-loop guarantees >=1 edge)
    for (; k < end; k += 8) {
        const int i0 = k + sub;
        const int c0 = min(i0, last);
        const int s0 = (int)csr[c0];
        float w0 = lrelu_exp(a_s[(size_t)s0 * 2 + hh] + adh);
        if (i0 >= end) w0 = 0.f;
        uint4 v0 = *(const uint4*)&xl[(size_t)s0 * 64 + li * 8];
        wsum += w0;
        FMA8(v0, w0);
    }
    #pragma unroll
    for (int ofs = 8; ofs <= 32; ofs <<= 1) {
        wsum += __shfl_xor(wsum, ofs, 64);
        #pragma unroll
        for (int i = 0; i < 8; ++i) acc[i] += __shfl_xor(acc[i], ofs, 64);
    }
    if (sub == 0) {
        const float4 b1a = *(const float4*)&b1[li * 8];
        const float4 b1b = *(const float4*)&b1[li * 8 + 4];
        const float inv = 1.f / wsum;
        float h0 = elu_f(acc[0] * inv + b1a.x);
        float h1 = elu_f(acc[1] * inv + b1a.y);
        float h2 = elu_f(acc[2] * inv + b1a.z);
        float h3 = elu_f(acc[3] * inv + b1a.w);
        float h4 = elu_f(acc[4] * inv + b1b.x);
        float h5 = elu_f(acc[5] * inv + b1b.y);
        float h6 = elu_f(acc[6] * inv + b1b.z);
        float h7 = elu_f(acc[7] * inv + b1b.w);
        uint4 p;
        p.x = (unsigned)f2bf(h0) | ((unsigned)f2bf(h1) << 16);
        p.y = (unsigned)f2bf(h2) | ((unsigned)f2bf(h3) << 16);
        p.z = (unsigned)f2bf(h4) | ((unsigned)f2bf(h5) << 16);
        p.w = (unsigned)f2bf(h6) | ((unsigned)f2bf(h7) << 16);
        *(uint4*)&hout[(size_t)dst * 64 + li * 8] = p;
    }
}

// ---------------- GEMM2 via MFMA: xl2(fp8) = h @ W2, fused attention dots ----
__global__ __launch_bounds__(256) void k_gemm2m(
    const unsigned short* __restrict__ h, const float* __restrict__ W2,
    const float* __restrict__ att_s, const float* __restrict__ att_d,
    unsigned char* __restrict__ xl2, float* __restrict__ a_s, float* __restrict__ a_d)
{
    __shared__ unsigned short W2T[128][72];  // W2^T bf16, pad 72 (18.4 KB)
    __shared__ float psA[4][16], psD[4][16];
    const int t = threadIdx.x, wave = t >> 6, lane = t & 63;
    const int quad = lane >> 4, lm = lane & 15;
    for (int i = t; i < 64 * 128; i += 256)
        W2T[i & 127][i >> 7] = f2bf(W2[i]);  // W2T[c][k] = W2[k][c]
    __syncthreads();

    const int c0 = wave * 32 + lm;
    const int c1 = c0 + 16;
    bf16x8 bfr0[2], bfr1[2];
    #pragma unroll
    for (int s = 0; s < 2; ++s) {
        bfr0[s] = *(const bf16x8*)&W2T[c0][s * 32 + quad * 8];
        bfr1[s] = *(const bf16x8*)&W2T[c1][s * 32 + quad * 8];
    }
    const float as0 = att_s[c0], as1 = att_s[c1];
    const float ad0 = att_d[c0], ad1 = att_d[c1];

    const int r0 = blockIdx.x * 16;
    f32x4 acc0 = {0.f, 0.f, 0.f, 0.f}, acc1 = {0.f, 0.f, 0.f, 0.f};
    #pragma unroll
    for (int s = 0; s < 2; ++s) {
        bf16x8 afr = *(const bf16x8*)&h[(size_t)(r0 + lm) * 64 + s * 32 + quad * 8];
        acc0 = __builtin_amdgcn_mfma_f32_16x16x32_bf16(afr, bfr0[s], acc0, 0, 0, 0);
        acc1 = __builtin_amdgcn_mfma_f32_16x16x32_bf16(afr, bfr1[s], acc1, 0, 0, 0);
    }
    float psv[4], pdv[4];
    #pragma unroll
    for (int r = 0; r < 4; ++r) {
        float v0 = acc0[r], v1 = acc1[r];
        const size_t row = (size_t)(r0 + quad * 4 + r) * 128;
        xl2[row + c0] = f2fp8(v0);          // fp8 e4m3 gather table
        xl2[row + c1] = f2fp8(v1);
        psv[r] = v0 * as0 + v1 * as1;       // logits from fp32 (pre-quant)
        pdv[r] = v0 * ad0 + v1 * ad1;
    }
    #pragma unroll
    for (int ofs = 1; ofs <= 8; ofs <<= 1) {
        #pragma unroll
        for (int r = 0; r < 4; ++r) {
            psv[r] += __shfl_xor(psv[r], ofs, 64);
            pdv[r] += __shfl_xor(pdv[r], ofs, 64);
        }
    }
    if (lm == 0) {
        #pragma unroll
        for (int r = 0; r < 4; ++r) {
            psA[wave][quad * 4 + r] = psv[r];
            psD[wave][quad * 4 + r] = pdv[r];
        }
    }
    __syncthreads();
    if (t < 16) {
        a_s[r0 + t] = psA[0][t] + psA[1][t] + psA[2][t] + psA[3][t];
        a_d[r0 + t] = psD[0][t] + psD[1][t] + psD[2][t] + psD[3][t];
    }
}

// ------- layer-2 attention: 128-thr blocks (2 dsts), fp8 gather, bf16 out ---
#define CFMA16(vv, ww) do { \
    f32x2 p_; \
    p_ = __builtin_amdgcn_cvt_pk_f32_fp8(vv.x, false); acc[0]  = fmaf(p_.x, ww, acc[0]);  acc[1]  = fmaf(p_.y, ww, acc[1]);  \
    p_ = __builtin_amdgcn_cvt_pk_f32_fp8(vv.x, true);  acc[2]  = fmaf(p_.x, ww, acc[2]);  acc[3]  = fmaf(p_.y, ww, acc[3]);  \
    p_ = __builtin_amdgcn_cvt_pk_f32_fp8(vv.y, false); acc[4]  = fmaf(p_.x, ww, acc[4]);  acc[5]  = fmaf(p_.y, ww, acc[5]);  \
    p_ = __builtin_amdgcn_cvt_pk_f32_fp8(vv.y, true);  acc[6]  = fmaf(p_.x, ww, acc[6]);  acc[7]  = fmaf(p_.y, ww, acc[7]);  \
    p_ = __builtin_amdgcn_cvt_pk_f32_fp8(vv.z, false); acc[8]  = fmaf(p_.x, ww, acc[8]);  acc[9]  = fmaf(p_.y, ww, acc[9]);  \
    p_ = __builtin_amdgcn_cvt_pk_f32_fp8(vv.z, true);  acc[10] = fmaf(p_.x, ww, acc[10]); acc[11] = fmaf(p_.y, ww, acc[11]); \
    p_ = __builtin_amdgcn_cvt_pk_f32_fp8(vv.w, false); acc[12] = fmaf(p_.x, ww, acc[12]); acc[13] = fmaf(p_.y, ww, acc[13]); \
    p_ = __builtin_amdgcn_cvt_pk_f32_fp8(vv.w, true);  acc[14] = fmaf(p_.x, ww, acc[14]); acc[15] = fmaf(p_.y, ww, acc[15]); \
} while (0)

__global__ __launch_bounds__(128) void k_attn2(
    const int* __restrict__ beg_a, const int* __restrict__ end_a,
    const unsigned* __restrict__ csr,
    const float* __restrict__ a_s, const float* __restrict__ a_d,
    const unsigned char* __restrict__ xl, unsigned short* __restrict__ out)
{
    const int wave = threadIdx.x >> 6, lane = threadIdx.x & 63;
    const int dst = blockIdx.x * 2 + wave;
    const int beg = beg_a[dst], end = end_a[dst];
    const int li = lane & 7, sub = lane >> 3;   // ch group li*16..+15; edge slot
    const float ad0 = a_d[dst];                 // wave-uniform

    float acc[16];
    #pragma unroll
    for (int i = 0; i < 16; ++i) acc[i] = 0.f;
    float wsum = 0.f;

    int k = beg;
    // main loop: all 32 slots valid, no masks, no clamps
    for (; k + 32 <= end; k += 32) {
        const int i0 = k + sub;
        const int s0 = (int)csr[i0];
        const int s1 = (int)csr[i0 + 8];
        const int s2 = (int)csr[i0 + 16];
        const int s3 = (int)csr[i0 + 24];
        const float w0 = lrelu_exp(a_s[s0] + ad0);
        const float w1 = lrelu_exp(a_s[s1] + ad0);
        const float w2 = lrelu_exp(a_s[s2] + ad0);
        const float w3 = lrelu_exp(a_s[s3] + ad0);
        uint4 v0 = *(const uint4*)&xl[(size_t)s0 * 128 + li * 16];
        uint4 v1 = *(const uint4*)&xl[(size_t)s1 * 128 + li * 16];
        uint4 v2 = *(const uint4*)&xl[(size_t)s2 * 128 + li * 16];
        uint4 v3 = *(const uint4*)&xl[(size_t)s3 * 128 + li * 16];
        wsum += w0 + w1 + w2 + w3;
        CFMA16(v0, w0);
        CFMA16(v1, w1);
        CFMA16(v2, w2);
        CFMA16(v3, w3);
    }
    // tail: 8 edges per iteration, masked
    const int last = end - 1;
    for (; k < end; k += 8) {
        const int i0 = k + sub;
        const int c0 = min(i0, last);
        const int s0 = (int)csr[c0];
        float w0 = lrelu_exp(a_s[s0] + ad0);
        if (i0 >= end) w0 = 0.f;
        uint4 v0 = *(const uint4*)&xl[(size_t)s0 * 128 + li * 16];
        wsum += w0;
        CFMA16(v0, w0);
    }
    #pragma unroll
    for (int ofs = 8; ofs <= 32; ofs <<= 1) {
        wsum += __shfl_xor(wsum, ofs, 64);
        #pragma unroll
        for (int i = 0; i < 16; ++i) acc[i] += __shfl_xor(acc[i], ofs, 64);
    }
    if (sub == 0) {
        const float inv = 1.f / wsum;
        unsigned short* op = &out[(size_t)dst * 128 + li * 16];
        uint4 pa, pb;
        pa.x = (unsigned)f2bf(acc[0]  * inv) | ((unsigned)f2bf(acc[1]  * inv) << 16);
        pa.y = (unsigned)f2bf(acc[2]  * inv) | ((unsigned)f2bf(acc[3]  * inv) << 16);
        pa.z = (unsigned)f2bf(acc[4]  * inv) | ((unsigned)f2bf(acc[5]  * inv) << 16);
        pa.w = (unsigned)f2bf(acc[6]  * inv) | ((unsigned)f2bf(acc[7]  * inv) << 16);
        pb.x = (unsigned)f2bf(acc[8]  * inv) | ((unsigned)f2bf(acc[9]  * inv) << 16);
        pb.y = (unsigned)f2bf(acc[10] * inv) | ((unsigned)f2bf(acc[11] * inv) << 16);
        pb.z = (unsigned)f2bf(acc[12] * inv) | ((unsigned)f2bf(acc[13] * inv) << 16);
        pb.w = (unsigned)f2bf(acc[14] * inv) | ((unsigned)f2bf(acc[15] * inv) << 16);
        *(uint4*)op       = pa;
        *(uint4*)(op + 8) = pb;
    }
}

// ---------------- pooling: 32 nodes/block, 2 node-lanes x 128 ch (bf16 in) ---
__global__ __launch_bounds__(256) void k_pool(
    const unsigned short* __restrict__ out2, const float* __restrict__ b2,
    const int* __restrict__ batch, float* __restrict__ sums, float* __restrict__ cnts)
{
    const int c    = threadIdx.x & 127;
    const int half = threadIdx.x >> 7;
    const int n0   = blockIdx.x * PN;
    const int nb   = n0 + half;
    if (nb >= N_NODES) return;
    const float bc = b2[c];
    float acc = 0.f;
    int cur = batch[nb], cnt = 0;
    for (int i = half; i < PN; i += 2) {
        int n = n0 + i;
        if (n >= N_NODES) break;
        int g = batch[n];
        if (g != cur) {
            atomicAdd(&sums[cur * OUT_CH + c], acc);
            if (c == 0) atomicAdd(&cnts[cur], (float)cnt);
            acc = 0.f; cnt = 0; cur = g;
        }
        float v = __uint_as_float((unsigned)out2[(size_t)n * OUT_CH + c] << 16);
        acc += elu_f(v + bc);
        cnt++;
    }
    if (cnt > 0) {
        atomicAdd(&sums[cur * OUT_CH + c], acc);
        if (c == 0) atomicAdd(&cnts[cur], (float)cnt);
    }
}

__global__ __launch_bounds__(256) void k_final(
    const float* __restrict__ sums, const float* __restrict__ cnts,
    float* __restrict__ out)
{
    int i = blockIdx.x * 256 + threadIdx.x;
    if (i >= N_GRAPHS * OUT_CH) return;
    out[i] = sums[i] / fmaxf(cnts[i >> 7], 1.f);
}

extern "C" void kernel_launch(void* const* d_in, const int* in_sizes, int n_in,
                              void* d_out, int out_size, void* d_ws, size_t ws_size,
                              hipStream_t stream)
{
    const float* x    = (const float*)d_in[0];
    const int*   ei   = (const int*)d_in[1];
    const int*   batch= (const int*)d_in[2];
    const float* W1   = (const float*)d_in[3];
    const float* as1  = (const float*)d_in[4];
    const float* ad1  = (const float*)d_in[5];
    const float* b1   = (const float*)d_in[6];
    const float* W2   = (const float*)d_in[7];
    const float* as2  = (const float*)d_in[8];
    const float* ad2  = (const float*)d_in[9];
    const float* b2   = (const float*)d_in[10];

    float* ws = (float*)d_ws;
    size_t o = 0;
    unsigned short* xl1b = (unsigned short*)(ws + o); o += (size_t)N_NODES * C1 / 2;
    unsigned short* hbuf = (unsigned short*)(ws + o); o += (size_t)N_NODES * C1 / 2;
    unsigned char*  xl2q = (unsigned char*)(ws + o);  o += (size_t)N_NODES * OUT_CH / 4;
    float*    a_s1 = ws + o; o += (size_t)N_NODES * 2;
    float*    a_d1 = ws + o; o += (size_t)N_NODES * 2;
    float*    a_s2 = ws + o; o += (size_t)N_NODES;
    float*    a_d2 = ws + o; o += (size_t)N_NODES;
    unsigned short* out2b = (unsigned short*)(ws + o); o += (size_t)N_NODES * OUT_CH / 2;
    unsigned* bbuf = (unsigned*)(ws + o); o += (size_t)NBUCK * BCAP;
    int*      beg  = (int*)(ws + o); o += (size_t)N_NODES;
    int*      end  = (int*)(ws + o); o += (size_t)N_NODES;
    size_t zero_start = o;
    int*      gcur = (int*)(ws + o); o += (size_t)NBUCK;
    float*    sums = ws + o;         o += (size_t)N_GRAPHS * OUT_CH;
    float*    cnts = ws + o;         o += (size_t)N_GRAPHS;
    size_t zero_bytes = (o - zero_start) * sizeof(float);
    hipMemsetAsync(ws + zero_start, 0, zero_bytes, stream);

    k_g1bin<<<NCHUNKS + N_NODES / 16, 256, 0, stream>>>(
        x, W1, as1, ad1, xl1b, a_s1, a_d1, ei, gcur, bbuf);
    k_bsort<<<NBUCK, 256, 0, stream>>>(gcur, bbuf, beg, end);
    k_attn1<<<N_NODES / 2, 128, 0, stream>>>(beg, end, bbuf, a_s1, a_d1, xl1b, b1, hbuf);
    k_gemm2m<<<(N_NODES + 15) / 16, 256, 0, stream>>>(hbuf, W2, as2, ad2, xl2q, a_s2, a_d2);
    k_attn2<<<N_NODES / 2, 128, 0, stream>>>(beg, end, bbuf, a_s2, a_d2, xl2q, out2b);
    k_pool<<<(N_NODES + PN - 1) / PN, 256, 0, stream>>>(out2b, b2, batch, sums, cnts);
    k_final<<<(N_GRAPHS * OUT_CH + 255) / 256, 256, 0, stream>>>(sums, cnts, (float*)d_out);
}